// Round 5
// baseline (318.574 us; speedup 1.0000x reference)
//
#include <hip/hip_runtime.h>
#include <hip/hip_bf16.h>
#include <math.h>

#define BDIM 4
#define VDIM 8
#define NDIM 256
#define CDIM 768
#define HDIM 12
#define DHE  64
#define C3   (3*CDIM)
#define ROWS (BDIM*VDIM*NDIM)
#define KEYS (VDIM*NDIM)   // 2048
#define NTASK 1536         // 48 (b,h) x 8 v x 4 q-quarters

typedef __attribute__((ext_vector_type(8))) short short8;   // 8 bf16 = 4 VGPR
typedef __attribute__((ext_vector_type(4))) float float4v;  // MFMA acc

__device__ inline unsigned short f2bf(float f) {
    unsigned int u = __builtin_bit_cast(unsigned int, f);
    u += 0x7fffu + ((u >> 16) & 1u);   // RNE
    return (unsigned short)(u >> 16);
}

// packed f32x2 -> bf16x2 in a uint (low half = a, high half = b), RNE
__device__ __forceinline__ unsigned int pk2(float a, float b) {
    return (unsigned int)f2bf(a) | ((unsigned int)f2bf(b) << 16);
}

// 8 fp32 (two float4) -> uint4 of 8 bf16
__device__ __forceinline__ uint4 pk8(float4 a, float4 b) {
    uint4 r;
    r.x = pk2(a.x, a.y); r.y = pk2(a.z, a.w);
    r.z = pk2(b.x, b.y); r.w = pk2(b.z, b.w);
    return r;
}

// async 16B global -> LDS (wave-uniform base + lane*16; lane-order == LDS order)
__device__ __forceinline__ void gld_lds16(const unsigned short* g, unsigned short* l) {
    __builtin_amdgcn_global_load_lds(
        (const __attribute__((address_space(1))) void*)g,
        (__attribute__((address_space(3))) void*)l, 16, 0, 0);
}

// ---------------------------------------------------------------------------
// One-shot fp32 -> bf16 pre-cast of feats, w_qkv, w_out (memory-bound ~9us).
// ---------------------------------------------------------------------------
#define NA8 786432   // 8192*768/8
#define NW8 221184   // 2304*768/8
#define NO8 73728    //  768*768/8

__global__ __launch_bounds__(256) void cast_bf16_all(
    const float* __restrict__ fA, const float* __restrict__ fW,
    const float* __restrict__ fO,
    unsigned short* __restrict__ bA, unsigned short* __restrict__ bW,
    unsigned short* __restrict__ bO)
{
    const int gid = blockIdx.x * 256 + threadIdx.x;
    const float* src;
    unsigned short* dst;
    int idx;
    if (gid < NA8)            { src = fA; dst = bA; idx = gid; }
    else if (gid < NA8 + NW8) { src = fW; dst = bW; idx = gid - NA8; }
    else                      { src = fO; dst = bO; idx = gid - NA8 - NW8; }
    const float4* p = (const float4*)(src + (size_t)idx * 8);
    *(uint4*)(dst + (size_t)idx * 8) = pk8(p[0], p[1]);
}

// ---------------------------------------------------------------------------
// Fused QKV GEMM, m97 step-3 structure: bf16 inputs, global_load_lds width-16
// direct into linear [128][32] LDS tiles. V col-blocks (col0 >= 1536) write
// the TRANSPOSED vT buffer directly and skip qkv.
// ---------------------------------------------------------------------------
__global__ __launch_bounds__(256) void gemm_qkv_mfma(
    const unsigned short* __restrict__ A,    // feats bf16 [8192][768]
    const unsigned short* __restrict__ W,    // w_qkv bf16 [2304][768]
    const float* __restrict__ bias,
    unsigned short* __restrict__ out,        // qkv [8192][2304] bf16 (Q,K only)
    unsigned short* __restrict__ vT)         // [4][12][64][2048] bf16
{
    __shared__ __attribute__((aligned(16))) unsigned short As[128][32];
    __shared__ __attribute__((aligned(16))) unsigned short Ws[128][32];
    const int t = threadIdx.x;
    const int wave = t >> 6, lane = t & 63;
    const int m = lane & 15, quad = lane >> 4;
    const int wr = (wave >> 1) * 64, wc = (wave & 1) * 64;
    const int row0 = blockIdx.y * 128, col0 = blockIdx.x * 128;

    // staging: thread t owns row (t>>2), k-chunk (t&3)*8 -> LDS byte t*16
    const int sr = t >> 2, sk = (t & 3) * 8;
    const unsigned short* ag = &A[(size_t)(row0 + sr) * CDIM + sk];
    const unsigned short* wg = &W[(size_t)(col0 + sr) * CDIM + sk];
    unsigned short* la0 = &As[sr][sk];
    unsigned short* la1 = &As[64 + sr][sk];
    unsigned short* lw0 = &Ws[sr][sk];
    unsigned short* lw1 = &Ws[64 + sr][sk];

    float4v acc[4][4] = {};

    for (int k0 = 0; k0 < CDIM; k0 += 32) {
        gld_lds16(ag + k0, la0);
        gld_lds16(ag + (size_t)64 * CDIM + k0, la1);
        gld_lds16(wg + k0, lw0);
        gld_lds16(wg + (size_t)64 * CDIM + k0, lw1);
        __syncthreads();
        short8 a[4], b[4];
        #pragma unroll
        for (int rt = 0; rt < 4; rt++)
            a[rt] = *(const short8*)&As[wr + rt * 16 + m][quad * 8];
        #pragma unroll
        for (int ct = 0; ct < 4; ct++)
            b[ct] = *(const short8*)&Ws[wc + ct * 16 + m][quad * 8];
        #pragma unroll
        for (int rt = 0; rt < 4; rt++)
            #pragma unroll
            for (int ct = 0; ct < 4; ct++)
                acc[rt][ct] = __builtin_amdgcn_mfma_f32_16x16x32_bf16(
                    a[rt], b[ct], acc[rt][ct], 0, 0, 0);
        __syncthreads();
    }

    if (col0 < 2 * CDIM) {
        // Q/K epilogue -> qkv
        #pragma unroll
        for (int ct = 0; ct < 4; ct++) {
            const int col = col0 + wc + ct * 16 + m;
            const float bv = bias[col];
            #pragma unroll
            for (int rt = 0; rt < 4; rt++) {
                const size_t row = (size_t)row0 + wr + rt * 16 + quad * 4;
                #pragma unroll
                for (int r = 0; r < 4; r++)
                    out[(row + r) * C3 + col] = f2bf(acc[rt][ct][r] + bv);
            }
        }
    } else {
        // V epilogue -> transposed vT (4 consecutive keys per lane -> 8B)
        #pragma unroll
        for (int ct = 0; ct < 4; ct++) {
            const int vcol = col0 + wc + ct * 16 + m - 2 * CDIM;
            const int h = vcol >> 6, d = vcol & 63;
            const float bv = bias[col0 + wc + ct * 16 + m];
            #pragma unroll
            for (int rt = 0; rt < 4; rt++) {
                const int row = row0 + wr + rt * 16 + quad * 4;
                const int bidx = row >> 11, key = row & 2047;
                ushort4 pkv;
                pkv.x = f2bf(acc[rt][ct][0] + bv);
                pkv.y = f2bf(acc[rt][ct][1] + bv);
                pkv.z = f2bf(acc[rt][ct][2] + bv);
                pkv.w = f2bf(acc[rt][ct][3] + bv);
                *(ushort4*)&vT[((size_t)(bidx * HDIM + h) * DHE + d) * KEYS + key] = pkv;
            }
        }
    }
}

// ---------------------------------------------------------------------------
// MFMA flash attention. R5: PERSISTENT blocks + atomic work queue.
// R4 post-mortem: occupancy 20.6% vs 37.5% residency cap = static-assignment
// makespan (all 768 blocks resident from t=0; task length ~ nChunks varies
// 0..14 with per-batch ref count; max-sum-of-3 per CU dominates). Fix:
// 1536 tasks of 64 queries (16 q/wave) pulled dynamically via atomicAdd;
// light blocks grab 3-4 tasks, heavy grab 1-2 -> ~85-90% packing.
// Unlike R3: Vs STAYS in LDS (R3's regression was V-from-global latency on
// the PV chain, not the 64-q split). setprio removed (R4: null/-2%).
// LDS = Ks 16K + Vs 16K + Ps 9K = 41K -> still 3 blocks/CU.
// ---------------------------------------------------------------------------
__global__ __launch_bounds__(256, 3) void attn_mfma(
    const unsigned short* __restrict__ qkv,  // [8192][2304] bf16 (Q,K)
    const unsigned short* __restrict__ vT,   // [4][12][64][2048] bf16
    const int* __restrict__ is_ref,
    unsigned short* __restrict__ ctx,        // [8192][768] bf16
    int* __restrict__ counter)               // zeroed on stream before launch
{
    const int t = threadIdx.x, wave = t >> 6, lane = t & 63;
    const int m = lane & 15, quad = lane >> 4;

    __shared__ unsigned short Ks[128][64];   // [key][dim], dg' = dg ^ (key&7)
    __shared__ unsigned short Vs[64][128];   // [dim][key], kg' = kg ^ (dim&15)
    __shared__ unsigned short Ps[4][16][72]; // [wave][query][64-key half]
    __shared__ int task_s;

    const float c1 = 0.18033688f;  // 0.125 * log2(e)

    // staging thread coords
    const int k_key = t >> 3, k_dg = t & 7;    // key = i*32 + k_key
    const int v_dim = t >> 4, v_kg = t & 15;   // dim = i*16 + v_dim

    for (;;) {
        if (t == 0) task_s = atomicAdd(counter, 1);
        __syncthreads();
        const int task = task_s;
        if (task >= NTASK) break;

        const int grp = task >> 5;           // 0..47 = (b,h); queue drains
        const int sub = task & 31;           //   grp-by-grp -> K/V stays hot
        const int b = grp / HDIM, h = grp % HDIM;
        const int v = sub & 7, q4 = sub >> 3;
        const int n0 = q4 * 64 + wave * 16;  // 16 queries per wave

        const int my_ref = is_ref[b * VDIM + v];
        unsigned amask = 0;
        #pragma unroll
        for (int w = 0; w < VDIM; w++)
            if ((is_ref[b * VDIM + w] != 0) ^ (my_ref != 0)) amask |= 1u << w;
        const int nChunks = 2 * __popc(amask);

        // Q B-frags: B[n=query=m][k=quad*8+j], two 32-dim K-steps
        short8 aq[2];
        {
            const size_t row = (size_t)((b * VDIM + v) * NDIM) + n0 + m;
            #pragma unroll
            for (int ks = 0; ks < 2; ks++)
                aq[ks] = *(const short8*)&qkv[row * C3 + h * DHE + ks * 32 + quad * 8];
        }

        float rs = 0.f;            // per-lane l partial, query = m
        float4v O[4] = {};

        const unsigned short* vTb = vT + (size_t)(b * HDIM + h) * DHE * KEYS;

        uint4 kreg[4], vreg[4];
        unsigned rem = amask;
        int wcur = __builtin_ffs((int)rem) - 1;

        if (nChunks > 0) {
            const unsigned short* kb =
                qkv + (size_t)((b * VDIM + wcur) * NDIM) * C3 + CDIM + h * DHE;
            #pragma unroll
            for (int i = 0; i < 4; i++)
                kreg[i] = *(const uint4*)&kb[(size_t)(i * 32 + k_key) * C3 + k_dg * 8];
            #pragma unroll
            for (int i = 0; i < 4; i++)
                vreg[i] = *(const uint4*)&vTb[(size_t)(i * 16 + v_dim) * KEYS
                                              + wcur * NDIM + v_kg * 8];
        }

        for (int ci = 0; ci < nChunks; ci++) {
            __syncthreads();   // prev chunk's LDS reads complete
            #pragma unroll
            for (int i = 0; i < 4; i++)
                *(uint4*)&Ks[i * 32 + k_key][(k_dg ^ (k_key & 7)) * 8] = kreg[i];
            #pragma unroll
            for (int i = 0; i < 4; i++)
                *(uint4*)&Vs[i * 16 + v_dim][(v_kg ^ v_dim) * 8] = vreg[i];

            if (ci + 1 < nChunks) {   // prefetch next chunk into regs
                int wn, m0n;
                if ((ci & 1) == 0) { wn = wcur; m0n = 128; }
                else {
                    unsigned r2 = rem & (rem - 1);
                    wn = __builtin_ffs((int)r2) - 1; m0n = 0;
                }
                const unsigned short* kb =
                    qkv + (size_t)((b * VDIM + wn) * NDIM + m0n) * C3 + CDIM + h * DHE;
                #pragma unroll
                for (int i = 0; i < 4; i++)
                    kreg[i] = *(const uint4*)&kb[(size_t)(i * 32 + k_key) * C3 + k_dg * 8];
                #pragma unroll
                for (int i = 0; i < 4; i++)
                    vreg[i] = *(const uint4*)&vTb[(size_t)(i * 16 + v_dim) * KEYS
                                                  + wn * NDIM + m0n + v_kg * 8];
            }
            __syncthreads();   // LDS tiles visible

            // two 64-key halves: S^T tiles -> packed Ps, then PV for that half
            #pragma unroll
            for (int hk = 0; hk < 2; hk++) {
                #pragma unroll
                for (int kt = 0; kt < 4; kt++) {
                    const int nt = hk * 4 + kt;
                    // A-frag = K (lane m = key within tile)
                    const short8 bk0 = *(const short8*)&Ks[nt * 16 + m][(quad ^ (m & 7)) * 8];
                    const short8 bk1 = *(const short8*)&Ks[nt * 16 + m][((4 + quad) ^ (m & 7)) * 8];
                    float4v s = {};
                    s = __builtin_amdgcn_mfma_f32_16x16x32_bf16(bk0, aq[0], s, 0, 0, 0);
                    s = __builtin_amdgcn_mfma_f32_16x16x32_bf16(bk1, aq[1], s, 0, 0, 0);
                    // s[r]: key = nt*16 + quad*4 + r, query = m
                    const float p0 = __builtin_amdgcn_exp2f(s[0] * c1);
                    const float p1 = __builtin_amdgcn_exp2f(s[1] * c1);
                    const float p2 = __builtin_amdgcn_exp2f(s[2] * c1);
                    const float p3 = __builtin_amdgcn_exp2f(s[3] * c1);
                    rs += (p0 + p1) + (p2 + p3);
                    uint2 pw;
                    pw.x = pk2(p0, p1);
                    pw.y = pk2(p2, p3);
                    *(uint2*)&Ps[wave][m][kt * 16 + quad * 4] = pw;
                }
                #pragma unroll
                for (int kk = 0; kk < 2; kk++) {
                    const short8 ap = *(const short8*)&Ps[wave][m][kk * 32 + quad * 8];
                    #pragma unroll
                    for (int ct = 0; ct < 4; ct++) {
                        const short8 bv = *(const short8*)&Vs[ct * 16 + m]
                            [((hk * 8 + kk * 4 + quad) ^ m) * 8];
                        O[ct] = __builtin_amdgcn_mfma_f32_16x16x32_bf16(ap, bv, O[ct], 0, 0, 0);
                    }
                }
            }
            if (ci & 1) { rem &= rem - 1; wcur = __builtin_ffs((int)rem) - 1; }
        }

        // final: reduce l across the 4 quad-copies, broadcast to O rows, write
        {
            float x = rs;
            x += __shfl_xor(x, 16, 64);
            x += __shfl_xor(x, 32, 64);
            const float inv = (x > 0.f) ? 1.f / x : 0.f;   // query = m
            float invq[4];
            #pragma unroll
            for (int r = 0; r < 4; r++)
                invq[r] = __shfl(inv, quad * 4 + r, 64);   // query = quad*4+r
            const size_t rowg = (size_t)((b * VDIM + v) * NDIM) + n0 + quad * 4;
            #pragma unroll
            for (int ct = 0; ct < 4; ct++)
                #pragma unroll
                for (int r = 0; r < 4; r++)
                    ctx[(rowg + r) * CDIM + h * DHE + ct * 16 + m] = f2bf(O[ct][r] * invq[r]);
        }
        __syncthreads();   // LDS reads + task_s read done before next fetch
    }
}

// ---------------------------------------------------------------------------
// Out-proj GEMM, global_load_lds staging; fp32 out + passthrough.
// ---------------------------------------------------------------------------
__global__ __launch_bounds__(256) void gemm_out_mfma(
    const unsigned short* __restrict__ A,   // ctx_b [8192][768] bf16
    const unsigned short* __restrict__ W,   // w_out bf16 [768][768]
    const float* __restrict__ bias,
    const float* __restrict__ feats,
    const int* __restrict__ is_ref,
    float* __restrict__ out)                // [8192][768] fp32
{
    __shared__ __attribute__((aligned(16))) unsigned short As[128][32];
    __shared__ __attribute__((aligned(16))) unsigned short Ws[128][32];
    const int t = threadIdx.x;
    const int wave = t >> 6, lane = t & 63;
    const int m = lane & 15, quad = lane >> 4;
    const int wr = (wave >> 1) * 64, wc = (wave & 1) * 64;
    const int row0 = blockIdx.y * 128, col0 = blockIdx.x * 128;

    const int sr = t >> 2, sk = (t & 3) * 8;
    const unsigned short* ag = &A[(size_t)(row0 + sr) * CDIM + sk];
    const unsigned short* wg = &W[(size_t)(col0 + sr) * CDIM + sk];
    unsigned short* la0 = &As[sr][sk];
    unsigned short* la1 = &As[64 + sr][sk];
    unsigned short* lw0 = &Ws[sr][sk];
    unsigned short* lw1 = &Ws[64 + sr][sk];

    float4v acc[4][4] = {};

    for (int k0 = 0; k0 < CDIM; k0 += 32) {
        gld_lds16(ag + k0, la0);
        gld_lds16(ag + (size_t)64 * CDIM + k0, la1);
        gld_lds16(wg + k0, lw0);
        gld_lds16(wg + (size_t)64 * CDIM + k0, lw1);
        __syncthreads();
        short8 a[4], b[4];
        #pragma unroll
        for (int rt = 0; rt < 4; rt++)
            a[rt] = *(const short8*)&As[wr + rt * 16 + m][quad * 8];
        #pragma unroll
        for (int ct = 0; ct < 4; ct++)
            b[ct] = *(const short8*)&Ws[wc + ct * 16 + m][quad * 8];
        #pragma unroll
        for (int rt = 0; rt < 4; rt++)
            #pragma unroll
            for (int ct = 0; ct < 4; ct++)
                acc[rt][ct] = __builtin_amdgcn_mfma_f32_16x16x32_bf16(
                    a[rt], b[ct], acc[rt][ct], 0, 0, 0);
        __syncthreads();
    }

    const int bidx = row0 / (VDIM * NDIM);
    const int vidx = (row0 / NDIM) % VDIM;
    const int my = is_ref[bidx * VDIM + vidx];
    bool has = false;
    #pragma unroll
    for (int w = 0; w < VDIM; w++) has = has || (is_ref[bidx * VDIM + w] != my);

    #pragma unroll
    for (int ct = 0; ct < 4; ct++) {
        const int col = col0 + wc + ct * 16 + m;
        const float bv = bias[col];
        #pragma unroll
        for (int rt = 0; rt < 4; rt++) {
            const size_t row = (size_t)row0 + wr + rt * 16 + quad * 4;
            #pragma unroll
            for (int r = 0; r < 4; r++) {
                float o = acc[rt][ct][r] + bv;
                if (!has) o = feats[(row + r) * CDIM + col];
                out[(row + r) * CDIM + col] = o;
            }
        }
    }
}

extern "C" void kernel_launch(void* const* d_in, const int* in_sizes, int n_in,
                              void* d_out, int out_size, void* d_ws, size_t ws_size,
                              hipStream_t stream) {
    const float* feats = (const float*)d_in[0];
    const int*   is_ref = (const int*)d_in[1];
    const float* w_qkv = (const float*)d_in[2];
    const float* b_qkv = (const float*)d_in[3];
    const float* w_out = (const float*)d_in[4];
    const float* b_out = (const float*)d_in[5];
    float* out = (float*)d_out;

    unsigned short* qkv_b = (unsigned short*)d_ws;                 // 8192x2304
    unsigned short* vT    = qkv_b + (size_t)ROWS * C3;             // 4x12x64x2048
    unsigned short* ctx_b = vT + (size_t)BDIM * HDIM * DHE * KEYS; // 8192x768
    unsigned short* A_bf  = ctx_b + (size_t)ROWS * CDIM;           // 8192x768
    unsigned short* Wq_bf = A_bf + (size_t)ROWS * CDIM;            // 2304x768
    unsigned short* Wo_bf = Wq_bf + (size_t)C3 * CDIM;             // 768x768
    int* counter = (int*)(Wo_bf + (size_t)CDIM * CDIM);

    cast_bf16_all<<<dim3((NA8 + NW8 + NO8) / 256), 256, 0, stream>>>(
        feats, w_qkv, w_out, A_bf, Wq_bf, Wo_bf);

    dim3 g1(C3 / 128, ROWS / 128);                                 // 18 x 64
    gemm_qkv_mfma<<<g1, 256, 0, stream>>>(A_bf, Wq_bf, b_qkv, qkv_b, vT);

    hipMemsetAsync(counter, 0, sizeof(int), stream);
    attn_mfma<<<dim3(768), 256, 0, stream>>>(qkv_b, vT, is_ref, ctx_b, counter);

    dim3 g3(CDIM / 128, ROWS / 128);                               // 6 x 64
    gemm_out_mfma<<<g3, 256, 0, stream>>>(ctx_b, Wo_bf, b_out, feats, is_ref, out);
    (void)in_sizes; (void)n_in; (void)out_size; (void)ws_size;
}

// Round 6
// 305.933 us; speedup vs baseline: 1.0413x; 1.0413x over previous
//
#include <hip/hip_runtime.h>
#include <hip/hip_bf16.h>
#include <math.h>

#define BDIM 4
#define VDIM 8
#define NDIM 256
#define CDIM 768
#define HDIM 12
#define DHE  64
#define C3   (3*CDIM)
#define ROWS (BDIM*VDIM*NDIM)
#define KEYS (VDIM*NDIM)   // 2048

typedef __attribute__((ext_vector_type(8))) short short8;   // 8 bf16 = 4 VGPR
typedef __attribute__((ext_vector_type(4))) float float4v;  // MFMA acc

__device__ inline unsigned short f2bf(float f) {
    unsigned int u = __builtin_bit_cast(unsigned int, f);
    u += 0x7fffu + ((u >> 16) & 1u);   // RNE
    return (unsigned short)(u >> 16);
}

// packed f32x2 -> bf16x2 in a uint (low half = a, high half = b), RNE
__device__ __forceinline__ unsigned int pk2(float a, float b) {
    return (unsigned int)f2bf(a) | ((unsigned int)f2bf(b) << 16);
}

// 8 fp32 (two float4) -> uint4 of 8 bf16
__device__ __forceinline__ uint4 pk8(float4 a, float4 b) {
    uint4 r;
    r.x = pk2(a.x, a.y); r.y = pk2(a.z, a.w);
    r.z = pk2(b.x, b.y); r.w = pk2(b.z, b.w);
    return r;
}

// async 16B global -> LDS (wave-uniform base + lane*16; lane-order == LDS order)
__device__ __forceinline__ void gld_lds16(const unsigned short* g, unsigned short* l) {
    __builtin_amdgcn_global_load_lds(
        (const __attribute__((address_space(1))) void*)g,
        (__attribute__((address_space(3))) void*)l, 16, 0, 0);
}

// ---------------------------------------------------------------------------
// One-shot fp32 -> bf16 pre-cast of feats, w_qkv, w_out (memory-bound ~9us).
// ---------------------------------------------------------------------------
#define NA8 786432   // 8192*768/8
#define NW8 221184   // 2304*768/8
#define NO8 73728    //  768*768/8

__global__ __launch_bounds__(256) void cast_bf16_all(
    const float* __restrict__ fA, const float* __restrict__ fW,
    const float* __restrict__ fO,
    unsigned short* __restrict__ bA, unsigned short* __restrict__ bW,
    unsigned short* __restrict__ bO)
{
    const int gid = blockIdx.x * 256 + threadIdx.x;
    const float* src;
    unsigned short* dst;
    int idx;
    if (gid < NA8)            { src = fA; dst = bA; idx = gid; }
    else if (gid < NA8 + NW8) { src = fW; dst = bW; idx = gid - NA8; }
    else                      { src = fO; dst = bO; idx = gid - NA8 - NW8; }
    const float4* p = (const float4*)(src + (size_t)idx * 8);
    *(uint4*)(dst + (size_t)idx * 8) = pk8(p[0], p[1]);
}

// ---------------------------------------------------------------------------
// LPT schedule: 768 tasks (grp = (b,h), sub = (half,v)); length class =
// popc(amask) in 0..8, known from is_ref alone. Stable counting sort DESC
// (stable -> same-grp tasks stay adjacent -> L2 locality kept). attn reads
// perm via a snake over 3 rounds of 256 so each CU gets long+short+medium.
// Per-batch r refs: ref-view tasks run 2(8-r) chunks, non-ref 2r -> R2's
// consecutive-gid map put equal-length tasks on one CU (53% packing).
// ---------------------------------------------------------------------------
__global__ __launch_bounds__(256) void sched_tasks(
    const int* __restrict__ is_ref, int* __restrict__ perm)
{
    __shared__ unsigned char lenS[768];
    __shared__ int base[9];
    const int t = threadIdx.x;
    for (int i = t; i < 768; i += 256) {
        const int grp = i >> 4, sub = i & 15;
        const int b = grp / HDIM, v = sub & 7;
        const int my = is_ref[b * VDIM + v];
        int cnt = 0;
        #pragma unroll
        for (int w = 0; w < VDIM; w++)
            if ((is_ref[b * VDIM + w] != 0) != (my != 0)) cnt++;
        lenS[i] = (unsigned char)cnt;
    }
    __syncthreads();
    if (t < 9) {
        int c = 0;
        for (int i = 0; i < 768; i++) if (lenS[i] == t) c++;
        base[t] = c;
    }
    __syncthreads();
    if (t == 0) {   // descending buckets: class 8 first
        int acc = 0;
        for (int j = 8; j >= 0; j--) { int c = base[j]; base[j] = acc; acc += c; }
    }
    __syncthreads();
    for (int i = t; i < 768; i += 256) {
        const int L = lenS[i];
        int rank = 0;
        for (int k = 0; k < i; k++) rank += (lenS[k] == L);
        perm[base[L] + rank] = i;
    }
}

// ---------------------------------------------------------------------------
// Fused QKV GEMM, m97 step-3 structure: bf16 inputs, global_load_lds width-16
// direct into linear [128][32] LDS tiles. V col-blocks (col0 >= 1536) write
// the TRANSPOSED vT buffer directly and skip qkv.
// ---------------------------------------------------------------------------
__global__ __launch_bounds__(256) void gemm_qkv_mfma(
    const unsigned short* __restrict__ A,    // feats bf16 [8192][768]
    const unsigned short* __restrict__ W,    // w_qkv bf16 [2304][768]
    const float* __restrict__ bias,
    unsigned short* __restrict__ out,        // qkv [8192][2304] bf16 (Q,K only)
    unsigned short* __restrict__ vT)         // [4][12][64][2048] bf16
{
    __shared__ __attribute__((aligned(16))) unsigned short As[128][32];
    __shared__ __attribute__((aligned(16))) unsigned short Ws[128][32];
    const int t = threadIdx.x;
    const int wave = t >> 6, lane = t & 63;
    const int m = lane & 15, quad = lane >> 4;
    const int wr = (wave >> 1) * 64, wc = (wave & 1) * 64;
    const int row0 = blockIdx.y * 128, col0 = blockIdx.x * 128;

    // staging: thread t owns row (t>>2), k-chunk (t&3)*8 -> LDS byte t*16
    const int sr = t >> 2, sk = (t & 3) * 8;
    const unsigned short* ag = &A[(size_t)(row0 + sr) * CDIM + sk];
    const unsigned short* wg = &W[(size_t)(col0 + sr) * CDIM + sk];
    unsigned short* la0 = &As[sr][sk];
    unsigned short* la1 = &As[64 + sr][sk];
    unsigned short* lw0 = &Ws[sr][sk];
    unsigned short* lw1 = &Ws[64 + sr][sk];

    float4v acc[4][4] = {};

    for (int k0 = 0; k0 < CDIM; k0 += 32) {
        gld_lds16(ag + k0, la0);
        gld_lds16(ag + (size_t)64 * CDIM + k0, la1);
        gld_lds16(wg + k0, lw0);
        gld_lds16(wg + (size_t)64 * CDIM + k0, lw1);
        __syncthreads();
        short8 a[4], b[4];
        #pragma unroll
        for (int rt = 0; rt < 4; rt++)
            a[rt] = *(const short8*)&As[wr + rt * 16 + m][quad * 8];
        #pragma unroll
        for (int ct = 0; ct < 4; ct++)
            b[ct] = *(const short8*)&Ws[wc + ct * 16 + m][quad * 8];
        #pragma unroll
        for (int rt = 0; rt < 4; rt++)
            #pragma unroll
            for (int ct = 0; ct < 4; ct++)
                acc[rt][ct] = __builtin_amdgcn_mfma_f32_16x16x32_bf16(
                    a[rt], b[ct], acc[rt][ct], 0, 0, 0);
        __syncthreads();
    }

    if (col0 < 2 * CDIM) {
        // Q/K epilogue -> qkv
        #pragma unroll
        for (int ct = 0; ct < 4; ct++) {
            const int col = col0 + wc + ct * 16 + m;
            const float bv = bias[col];
            #pragma unroll
            for (int rt = 0; rt < 4; rt++) {
                const size_t row = (size_t)row0 + wr + rt * 16 + quad * 4;
                #pragma unroll
                for (int r = 0; r < 4; r++)
                    out[(row + r) * C3 + col] = f2bf(acc[rt][ct][r] + bv);
            }
        }
    } else {
        // V epilogue -> transposed vT (4 consecutive keys per lane -> 8B)
        #pragma unroll
        for (int ct = 0; ct < 4; ct++) {
            const int vcol = col0 + wc + ct * 16 + m - 2 * CDIM;
            const int h = vcol >> 6, d = vcol & 63;
            const float bv = bias[col0 + wc + ct * 16 + m];
            #pragma unroll
            for (int rt = 0; rt < 4; rt++) {
                const int row = row0 + wr + rt * 16 + quad * 4;
                const int bidx = row >> 11, key = row & 2047;
                ushort4 pkv;
                pkv.x = f2bf(acc[rt][ct][0] + bv);
                pkv.y = f2bf(acc[rt][ct][1] + bv);
                pkv.z = f2bf(acc[rt][ct][2] + bv);
                pkv.w = f2bf(acc[rt][ct][3] + bv);
                *(ushort4*)&vT[((size_t)(bidx * HDIM + h) * DHE + d) * KEYS + key] = pkv;
            }
        }
    }
}

// ---------------------------------------------------------------------------
// MFMA flash attention. R6 = R2 known-best inner structure (128 q/block,
// Ks+Vs+Ps in LDS, grid 768, 3 blocks/CU, no setprio) + LPT-snake task
// lookup. Dispatch maps block g -> CU (g%8,(g/8)%32); g and g+256 share a
// CU, so round r = g>>8 with a reversed middle round balances per-CU sums.
// ---------------------------------------------------------------------------
__global__ __launch_bounds__(256, 3) void attn_mfma(
    const unsigned short* __restrict__ qkv,  // [8192][2304] bf16 (Q,K)
    const unsigned short* __restrict__ vT,   // [4][12][64][2048] bf16
    const int* __restrict__ is_ref,
    unsigned short* __restrict__ ctx,        // [8192][768] bf16
    const int* __restrict__ perm)            // LPT order from sched_tasks
{
    const int g = blockIdx.x;
    const int round = g >> 8, cu = g & 255;
    const int idx = (round & 1) ? ((round << 8) | (255 - cu)) : g;
    const int task = perm[idx];
    const int grp = task >> 4;               // (b,h)
    const int sub = task & 15;               // (half, v)
    const int b = grp / HDIM, h = grp % HDIM;
    const int v = sub & 7, half = sub >> 3;

    const int t = threadIdx.x, wave = t >> 6, lane = t & 63;
    const int m = lane & 15, quad = lane >> 4;
    const int n0 = half * 128 + wave * 32;

    __shared__ unsigned short Ks[128][64];   // [key][dim], dg' = dg ^ (key&7)
    __shared__ unsigned short Vs[64][128];   // [dim][key], kg' = kg ^ (dim&15)
    __shared__ unsigned short Ps[4][32][72]; // [wave][query][64-key half]

    const int my_ref = is_ref[b * VDIM + v];
    unsigned amask = 0;
    #pragma unroll
    for (int w = 0; w < VDIM; w++)
        if ((is_ref[b * VDIM + w] != 0) ^ (my_ref != 0)) amask |= 1u << w;
    const int nChunks = 2 * __popc(amask);

    const float c1 = 0.18033688f;  // 0.125 * log2(e)

    // Q B-frags: B[n=query=m][k=quad*8+j], two 32-dim K-steps
    short8 aq[2][2];
    #pragma unroll
    for (int qt = 0; qt < 2; qt++) {
        const size_t row = (size_t)((b * VDIM + v) * NDIM) + n0 + qt * 16 + m;
        #pragma unroll
        for (int ks = 0; ks < 2; ks++)
            aq[qt][ks] = *(const short8*)&qkv[row * C3 + h * DHE + ks * 32 + quad * 8];
    }

    float rs[2] = {0.f, 0.f};     // per-lane l partial, query = qt*16 + m
    float4v O[2][4] = {};

    // staging thread coords
    const int k_key = t >> 3, k_dg = t & 7;    // key = i*32 + k_key
    const int v_dim = t >> 4, v_kg = t & 15;   // dim = i*16 + v_dim

    const unsigned short* vTb = vT + (size_t)(b * HDIM + h) * DHE * KEYS;

    uint4 kreg[4], vreg[4];
    unsigned rem = amask;
    int wcur = __builtin_ffs((int)rem) - 1;

    if (nChunks > 0) {
        const unsigned short* kb =
            qkv + (size_t)((b * VDIM + wcur) * NDIM) * C3 + CDIM + h * DHE;
        #pragma unroll
        for (int i = 0; i < 4; i++)
            kreg[i] = *(const uint4*)&kb[(size_t)(i * 32 + k_key) * C3 + k_dg * 8];
        #pragma unroll
        for (int i = 0; i < 4; i++)
            vreg[i] = *(const uint4*)&vTb[(size_t)(i * 16 + v_dim) * KEYS
                                          + wcur * NDIM + v_kg * 8];
    }

    for (int ci = 0; ci < nChunks; ci++) {
        __syncthreads();   // prev chunk's LDS reads complete
        #pragma unroll
        for (int i = 0; i < 4; i++)
            *(uint4*)&Ks[i * 32 + k_key][(k_dg ^ (k_key & 7)) * 8] = kreg[i];
        #pragma unroll
        for (int i = 0; i < 4; i++)
            *(uint4*)&Vs[i * 16 + v_dim][(v_kg ^ v_dim) * 8] = vreg[i];

        if (ci + 1 < nChunks) {   // prefetch next chunk into regs
            int wn, m0n;
            if ((ci & 1) == 0) { wn = wcur; m0n = 128; }
            else {
                unsigned r2 = rem & (rem - 1);
                wn = __builtin_ffs((int)r2) - 1; m0n = 0;
            }
            const unsigned short* kb =
                qkv + (size_t)((b * VDIM + wn) * NDIM + m0n) * C3 + CDIM + h * DHE;
            #pragma unroll
            for (int i = 0; i < 4; i++)
                kreg[i] = *(const uint4*)&kb[(size_t)(i * 32 + k_key) * C3 + k_dg * 8];
            #pragma unroll
            for (int i = 0; i < 4; i++)
                vreg[i] = *(const uint4*)&vTb[(size_t)(i * 16 + v_dim) * KEYS
                                              + wn * NDIM + m0n + v_kg * 8];
        }
        __syncthreads();   // LDS tiles visible

        // two 64-key halves: S^T tiles -> packed Ps, then PV for that half
        #pragma unroll
        for (int hk = 0; hk < 2; hk++) {
            #pragma unroll
            for (int kt = 0; kt < 4; kt++) {
                const int nt = hk * 4 + kt;
                // A-frag = K (lane m = key within tile)
                const short8 bk0 = *(const short8*)&Ks[nt * 16 + m][(quad ^ (m & 7)) * 8];
                const short8 bk1 = *(const short8*)&Ks[nt * 16 + m][((4 + quad) ^ (m & 7)) * 8];
                #pragma unroll
                for (int qt = 0; qt < 2; qt++) {
                    float4v s = {};
                    s = __builtin_amdgcn_mfma_f32_16x16x32_bf16(bk0, aq[qt][0], s, 0, 0, 0);
                    s = __builtin_amdgcn_mfma_f32_16x16x32_bf16(bk1, aq[qt][1], s, 0, 0, 0);
                    // s[r]: key = nt*16 + quad*4 + r, query = qt*16 + m
                    const float p0 = __builtin_amdgcn_exp2f(s[0] * c1);
                    const float p1 = __builtin_amdgcn_exp2f(s[1] * c1);
                    const float p2 = __builtin_amdgcn_exp2f(s[2] * c1);
                    const float p3 = __builtin_amdgcn_exp2f(s[3] * c1);
                    rs[qt] += (p0 + p1) + (p2 + p3);
                    uint2 pw;
                    pw.x = pk2(p0, p1);
                    pw.y = pk2(p2, p3);
                    *(uint2*)&Ps[wave][qt * 16 + m][kt * 16 + quad * 4] = pw;
                }
            }
            #pragma unroll
            for (int kk = 0; kk < 2; kk++) {
                const short8 ap0 = *(const short8*)&Ps[wave][m][kk * 32 + quad * 8];
                const short8 ap1 = *(const short8*)&Ps[wave][16 + m][kk * 32 + quad * 8];
                #pragma unroll
                for (int ct = 0; ct < 4; ct++) {
                    const short8 bv = *(const short8*)&Vs[ct * 16 + m]
                        [((hk * 8 + kk * 4 + quad) ^ m) * 8];
                    O[0][ct] = __builtin_amdgcn_mfma_f32_16x16x32_bf16(ap0, bv, O[0][ct], 0, 0, 0);
                    O[1][ct] = __builtin_amdgcn_mfma_f32_16x16x32_bf16(ap1, bv, O[1][ct], 0, 0, 0);
                }
            }
        }
        if (ci & 1) { rem &= rem - 1; wcur = __builtin_ffs((int)rem) - 1; }
    }

    // final: reduce l across the 4 quad-copies, broadcast to O rows, write
    #pragma unroll
    for (int qt = 0; qt < 2; qt++) {
        float x = rs[qt];
        x += __shfl_xor(x, 16, 64);
        x += __shfl_xor(x, 32, 64);
        const float inv = (x > 0.f) ? 1.f / x : 0.f;   // query = qt*16 + m
        float invq[4];
        #pragma unroll
        for (int r = 0; r < 4; r++)
            invq[r] = __shfl(inv, quad * 4 + r, 64);   // query = qt*16+quad*4+r
        const size_t rowg = (size_t)((b * VDIM + v) * NDIM) + n0 + qt * 16 + quad * 4;
        #pragma unroll
        for (int ct = 0; ct < 4; ct++)
            #pragma unroll
            for (int r = 0; r < 4; r++)
                ctx[(rowg + r) * CDIM + h * DHE + ct * 16 + m] = f2bf(O[qt][ct][r] * invq[r]);
    }
}

// ---------------------------------------------------------------------------
// Out-proj GEMM, global_load_lds staging; fp32 out + passthrough.
// ---------------------------------------------------------------------------
__global__ __launch_bounds__(256) void gemm_out_mfma(
    const unsigned short* __restrict__ A,   // ctx_b [8192][768] bf16
    const unsigned short* __restrict__ W,   // w_out bf16 [768][768]
    const float* __restrict__ bias,
    const float* __restrict__ feats,
    const int* __restrict__ is_ref,
    float* __restrict__ out)                // [8192][768] fp32
{
    __shared__ __attribute__((aligned(16))) unsigned short As[128][32];
    __shared__ __attribute__((aligned(16))) unsigned short Ws[128][32];
    const int t = threadIdx.x;
    const int wave = t >> 6, lane = t & 63;
    const int m = lane & 15, quad = lane >> 4;
    const int wr = (wave >> 1) * 64, wc = (wave & 1) * 64;
    const int row0 = blockIdx.y * 128, col0 = blockIdx.x * 128;

    const int sr = t >> 2, sk = (t & 3) * 8;
    const unsigned short* ag = &A[(size_t)(row0 + sr) * CDIM + sk];
    const unsigned short* wg = &W[(size_t)(col0 + sr) * CDIM + sk];
    unsigned short* la0 = &As[sr][sk];
    unsigned short* la1 = &As[64 + sr][sk];
    unsigned short* lw0 = &Ws[sr][sk];
    unsigned short* lw1 = &Ws[64 + sr][sk];

    float4v acc[4][4] = {};

    for (int k0 = 0; k0 < CDIM; k0 += 32) {
        gld_lds16(ag + k0, la0);
        gld_lds16(ag + (size_t)64 * CDIM + k0, la1);
        gld_lds16(wg + k0, lw0);
        gld_lds16(wg + (size_t)64 * CDIM + k0, lw1);
        __syncthreads();
        short8 a[4], b[4];
        #pragma unroll
        for (int rt = 0; rt < 4; rt++)
            a[rt] = *(const short8*)&As[wr + rt * 16 + m][quad * 8];
        #pragma unroll
        for (int ct = 0; ct < 4; ct++)
            b[ct] = *(const short8*)&Ws[wc + ct * 16 + m][quad * 8];
        #pragma unroll
        for (int rt = 0; rt < 4; rt++)
            #pragma unroll
            for (int ct = 0; ct < 4; ct++)
                acc[rt][ct] = __builtin_amdgcn_mfma_f32_16x16x32_bf16(
                    a[rt], b[ct], acc[rt][ct], 0, 0, 0);
        __syncthreads();
    }

    const int bidx = row0 / (VDIM * NDIM);
    const int vidx = (row0 / NDIM) % VDIM;
    const int my = is_ref[bidx * VDIM + vidx];
    bool has = false;
    #pragma unroll
    for (int w = 0; w < VDIM; w++) has = has || (is_ref[bidx * VDIM + w] != my);

    #pragma unroll
    for (int ct = 0; ct < 4; ct++) {
        const int col = col0 + wc + ct * 16 + m;
        const float bv = bias[col];
        #pragma unroll
        for (int rt = 0; rt < 4; rt++) {
            const size_t row = (size_t)row0 + wr + rt * 16 + quad * 4;
            #pragma unroll
            for (int r = 0; r < 4; r++) {
                float o = acc[rt][ct][r] + bv;
                if (!has) o = feats[(row + r) * CDIM + col];
                out[(row + r) * CDIM + col] = o;
            }
        }
    }
}

extern "C" void kernel_launch(void* const* d_in, const int* in_sizes, int n_in,
                              void* d_out, int out_size, void* d_ws, size_t ws_size,
                              hipStream_t stream) {
    const float* feats = (const float*)d_in[0];
    const int*   is_ref = (const int*)d_in[1];
    const float* w_qkv = (const float*)d_in[2];
    const float* b_qkv = (const float*)d_in[3];
    const float* w_out = (const float*)d_in[4];
    const float* b_out = (const float*)d_in[5];
    float* out = (float*)d_out;

    unsigned short* qkv_b = (unsigned short*)d_ws;                 // 8192x2304
    unsigned short* vT    = qkv_b + (size_t)ROWS * C3;             // 4x12x64x2048
    unsigned short* ctx_b = vT + (size_t)BDIM * HDIM * DHE * KEYS; // 8192x768
    unsigned short* A_bf  = ctx_b + (size_t)ROWS * CDIM;           // 8192x768
    unsigned short* Wq_bf = A_bf + (size_t)ROWS * CDIM;            // 2304x768
    unsigned short* Wo_bf = Wq_bf + (size_t)C3 * CDIM;             // 768x768
    int* perm = (int*)(Wo_bf + (size_t)CDIM * CDIM);               // 768 ints

    sched_tasks<<<dim3(1), 256, 0, stream>>>(is_ref, perm);

    cast_bf16_all<<<dim3((NA8 + NW8 + NO8) / 256), 256, 0, stream>>>(
        feats, w_qkv, w_out, A_bf, Wq_bf, Wo_bf);

    dim3 g1(C3 / 128, ROWS / 128);                                 // 18 x 64
    gemm_qkv_mfma<<<g1, 256, 0, stream>>>(A_bf, Wq_bf, b_qkv, qkv_b, vT);

    attn_mfma<<<dim3(768), 256, 0, stream>>>(qkv_b, vT, is_ref, ctx_b, perm);

    dim3 g3(CDIM / 128, ROWS / 128);                               // 6 x 64
    gemm_out_mfma<<<g3, 256, 0, stream>>>(ctx_b, Wo_bf, b_out, feats, is_ref, out);
    (void)in_sizes; (void)n_in; (void)out_size; (void)ws_size;
}

// Round 7
// 251.835 us; speedup vs baseline: 1.2650x; 1.2148x over previous
//
#include <hip/hip_runtime.h>
#include <hip/hip_bf16.h>
#include <math.h>

#define BDIM 4
#define VDIM 8
#define NDIM 256
#define CDIM 768
#define HDIM 12
#define DHE  64
#define C3   (3*CDIM)
#define ROWS (BDIM*VDIM*NDIM)
#define KEYS (VDIM*NDIM)   // 2048

typedef __attribute__((ext_vector_type(8))) short short8;   // 8 bf16 = 4 VGPR
typedef __attribute__((ext_vector_type(4))) float float4v;  // MFMA acc

__device__ inline unsigned short f2bf(float f) {
    unsigned int u = __builtin_bit_cast(unsigned int, f);
    u += 0x7fffu + ((u >> 16) & 1u);   // RNE
    return (unsigned short)(u >> 16);
}

// packed f32x2 -> bf16x2 in a uint (low half = a, high half = b), RNE
__device__ __forceinline__ unsigned int pk2(float a, float b) {
    return (unsigned int)f2bf(a) | ((unsigned int)f2bf(b) << 16);
}

// 8 fp32 (two float4) -> uint4 of 8 bf16
__device__ __forceinline__ uint4 pk8(float4 a, float4 b) {
    uint4 r;
    r.x = pk2(a.x, a.y); r.y = pk2(a.z, a.w);
    r.z = pk2(b.x, b.y); r.w = pk2(b.z, b.w);
    return r;
}

// async 16B global -> LDS (wave-uniform base + lane*16; lane-order == LDS order)
__device__ __forceinline__ void gld_lds16(const unsigned short* g, unsigned short* l) {
    __builtin_amdgcn_global_load_lds(
        (const __attribute__((address_space(1))) void*)g,
        (__attribute__((address_space(3))) void*)l, 16, 0, 0);
}

// ---------------------------------------------------------------------------
// One-shot fp32 -> bf16 pre-cast of feats, w_qkv, w_out (memory-bound ~9us).
// ---------------------------------------------------------------------------
#define NA8 786432   // 8192*768/8
#define NW8 221184   // 2304*768/8
#define NO8 73728    //  768*768/8

__global__ __launch_bounds__(256) void cast_bf16_all(
    const float* __restrict__ fA, const float* __restrict__ fW,
    const float* __restrict__ fO,
    unsigned short* __restrict__ bA, unsigned short* __restrict__ bW,
    unsigned short* __restrict__ bO)
{
    const int gid = blockIdx.x * 256 + threadIdx.x;
    const float* src;
    unsigned short* dst;
    int idx;
    if (gid < NA8)            { src = fA; dst = bA; idx = gid; }
    else if (gid < NA8 + NW8) { src = fW; dst = bW; idx = gid - NA8; }
    else                      { src = fO; dst = bO; idx = gid - NA8 - NW8; }
    const float4* p = (const float4*)(src + (size_t)idx * 8);
    *(uint4*)(dst + (size_t)idx * 8) = pk8(p[0], p[1]);
}

// ---------------------------------------------------------------------------
// Fused QKV GEMM, m97 step-3 structure: bf16 inputs, global_load_lds width-16
// direct into linear [128][32] LDS tiles. V col-blocks (col0 >= 1536) write
// the TRANSPOSED vT buffer directly and skip qkv.
// ---------------------------------------------------------------------------
__global__ __launch_bounds__(256) void gemm_qkv_mfma(
    const unsigned short* __restrict__ A,    // feats bf16 [8192][768]
    const unsigned short* __restrict__ W,    // w_qkv bf16 [2304][768]
    const float* __restrict__ bias,
    unsigned short* __restrict__ out,        // qkv [8192][2304] bf16 (Q,K only)
    unsigned short* __restrict__ vT)         // [4][12][64][2048] bf16
{
    __shared__ __attribute__((aligned(16))) unsigned short As[128][32];
    __shared__ __attribute__((aligned(16))) unsigned short Ws[128][32];
    const int t = threadIdx.x;
    const int wave = t >> 6, lane = t & 63;
    const int m = lane & 15, quad = lane >> 4;
    const int wr = (wave >> 1) * 64, wc = (wave & 1) * 64;
    const int row0 = blockIdx.y * 128, col0 = blockIdx.x * 128;

    // staging: thread t owns row (t>>2), k-chunk (t&3)*8 -> LDS byte t*16
    const int sr = t >> 2, sk = (t & 3) * 8;
    const unsigned short* ag = &A[(size_t)(row0 + sr) * CDIM + sk];
    const unsigned short* wg = &W[(size_t)(col0 + sr) * CDIM + sk];
    unsigned short* la0 = &As[sr][sk];
    unsigned short* la1 = &As[64 + sr][sk];
    unsigned short* lw0 = &Ws[sr][sk];
    unsigned short* lw1 = &Ws[64 + sr][sk];

    float4v acc[4][4] = {};

    for (int k0 = 0; k0 < CDIM; k0 += 32) {
        gld_lds16(ag + k0, la0);
        gld_lds16(ag + (size_t)64 * CDIM + k0, la1);
        gld_lds16(wg + k0, lw0);
        gld_lds16(wg + (size_t)64 * CDIM + k0, lw1);
        __syncthreads();
        short8 a[4], b[4];
        #pragma unroll
        for (int rt = 0; rt < 4; rt++)
            a[rt] = *(const short8*)&As[wr + rt * 16 + m][quad * 8];
        #pragma unroll
        for (int ct = 0; ct < 4; ct++)
            b[ct] = *(const short8*)&Ws[wc + ct * 16 + m][quad * 8];
        #pragma unroll
        for (int rt = 0; rt < 4; rt++)
            #pragma unroll
            for (int ct = 0; ct < 4; ct++)
                acc[rt][ct] = __builtin_amdgcn_mfma_f32_16x16x32_bf16(
                    a[rt], b[ct], acc[rt][ct], 0, 0, 0);
        __syncthreads();
    }

    if (col0 < 2 * CDIM) {
        // Q/K epilogue -> qkv
        #pragma unroll
        for (int ct = 0; ct < 4; ct++) {
            const int col = col0 + wc + ct * 16 + m;
            const float bv = bias[col];
            #pragma unroll
            for (int rt = 0; rt < 4; rt++) {
                const size_t row = (size_t)row0 + wr + rt * 16 + quad * 4;
                #pragma unroll
                for (int r = 0; r < 4; r++)
                    out[(row + r) * C3 + col] = f2bf(acc[rt][ct][r] + bv);
            }
        }
    } else {
        // V epilogue -> transposed vT (4 consecutive keys per lane -> 8B)
        #pragma unroll
        for (int ct = 0; ct < 4; ct++) {
            const int vcol = col0 + wc + ct * 16 + m - 2 * CDIM;
            const int h = vcol >> 6, d = vcol & 63;
            const float bv = bias[col0 + wc + ct * 16 + m];
            #pragma unroll
            for (int rt = 0; rt < 4; rt++) {
                const int row = row0 + wr + rt * 16 + quad * 4;
                const int bidx = row >> 11, key = row & 2047;
                ushort4 pkv;
                pkv.x = f2bf(acc[rt][ct][0] + bv);
                pkv.y = f2bf(acc[rt][ct][1] + bv);
                pkv.z = f2bf(acc[rt][ct][2] + bv);
                pkv.w = f2bf(acc[rt][ct][3] + bv);
                *(ushort4*)&vT[((size_t)(bidx * HDIM + h) * DHE + d) * KEYS + key] = pkv;
            }
        }
    }
}

// ---------------------------------------------------------------------------
// MFMA flash attention. R7: LPT-snake schedule derived ANALYTICALLY in-kernel.
// R6 post-mortem: the LPT idea gave attn 97->86us (occ 26.4%), but the
// 1-block sched_tasks kernel cost ~59us of serial LDS-latency rank loops on
// the stream critical path. The sorted order is a closed-form function of the
// 4 per-batch ref counts: bucket count for class L = sum_b 24*nv(b,L),
// nv(b,L) = (8-r_b==L ? r_b : 0) + (r_b==L ? 8-r_b : 0); within bucket the
// stable order is (b, h, half, v in class-set ascending). ~60 wave-uniform
// scalar ops per block. Any bijection is correct; LPT property identical.
// Inner loop = R2/R4 known-best structure, unchanged.
// ---------------------------------------------------------------------------
__global__ __launch_bounds__(256, 3) void attn_mfma(
    const unsigned short* __restrict__ qkv,  // [8192][2304] bf16 (Q,K)
    const unsigned short* __restrict__ vT,   // [4][12][64][2048] bf16
    const int* __restrict__ is_ref,
    unsigned short* __restrict__ ctx)        // [8192][768] bf16
{
    const int g = blockIdx.x;
    const int round = g >> 8, cu = g & 255;
    const int idx = (round & 1) ? ((round << 8) | (255 - cu)) : g;

    // ---- analytic LPT lookup: idx -> (b, h, half, v) ----
    int rmask[4], r4[4];
    #pragma unroll
    for (int bb = 0; bb < 4; bb++) {
        int mask = 0;
        #pragma unroll
        for (int w = 0; w < VDIM; w++)
            if (is_ref[bb * VDIM + w] != 0) mask |= 1 << w;
        rmask[bb] = mask; r4[bb] = __popc(mask);
    }
    int rr = idx, b = 0, nv = 0, Lsel = 0;
    bool found = false;
    for (int Lc = 8; Lc >= 0 && !found; Lc--) {
        for (int bb = 0; bb < 4 && !found; bb++) {
            int n = 0;
            if (8 - r4[bb] == Lc) n += r4[bb];          // ref views
            if (r4[bb] == Lc) n += 8 - r4[bb];          // non-ref views
            if (rr < 24 * n) { b = bb; nv = n; Lsel = Lc; found = true; }
            else rr -= 24 * n;
        }
    }
    const int h = rr / (2 * nv);
    const int rem = rr % (2 * nv);
    const int half = rem / nv;
    int pos = rem % nv;
    int S = 0;
    if (8 - r4[b] == Lsel) S |= rmask[b];
    if (r4[b] == Lsel) S |= (~rmask[b]) & 0xff;
    int v = 0;
    for (int vv = 0; vv < 8; vv++) {
        if ((S >> vv) & 1) { if (pos == 0) { v = vv; break; } pos--; }
    }
    // ------------------------------------------------------

    const int t = threadIdx.x, wave = t >> 6, lane = t & 63;
    const int m = lane & 15, quad = lane >> 4;
    const int n0 = half * 128 + wave * 32;

    __shared__ unsigned short Ks[128][64];   // [key][dim], dg' = dg ^ (key&7)
    __shared__ unsigned short Vs[64][128];   // [dim][key], kg' = kg ^ (dim&15)
    __shared__ unsigned short Ps[4][32][72]; // [wave][query][64-key half]

    const int my_ref = (rmask[b] >> v) & 1;
    const unsigned amask = my_ref ? (unsigned)((~rmask[b]) & 0xff)
                                  : (unsigned)rmask[b];
    const int nChunks = 2 * Lsel;

    const float c1 = 0.18033688f;  // 0.125 * log2(e)

    // Q B-frags: B[n=query=m][k=quad*8+j], two 32-dim K-steps
    short8 aq[2][2];
    #pragma unroll
    for (int qt = 0; qt < 2; qt++) {
        const size_t row = (size_t)((b * VDIM + v) * NDIM) + n0 + qt * 16 + m;
        #pragma unroll
        for (int ks = 0; ks < 2; ks++)
            aq[qt][ks] = *(const short8*)&qkv[row * C3 + h * DHE + ks * 32 + quad * 8];
    }

    float rs[2] = {0.f, 0.f};     // per-lane l partial, query = qt*16 + m
    float4v O[2][4] = {};

    // staging thread coords
    const int k_key = t >> 3, k_dg = t & 7;    // key = i*32 + k_key
    const int v_dim = t >> 4, v_kg = t & 15;   // dim = i*16 + v_dim

    const unsigned short* vTb = vT + (size_t)(b * HDIM + h) * DHE * KEYS;

    uint4 kreg[4], vreg[4];
    unsigned rem2 = amask;
    int wcur = __builtin_ffs((int)rem2) - 1;

    if (nChunks > 0) {
        const unsigned short* kb =
            qkv + (size_t)((b * VDIM + wcur) * NDIM) * C3 + CDIM + h * DHE;
        #pragma unroll
        for (int i = 0; i < 4; i++)
            kreg[i] = *(const uint4*)&kb[(size_t)(i * 32 + k_key) * C3 + k_dg * 8];
        #pragma unroll
        for (int i = 0; i < 4; i++)
            vreg[i] = *(const uint4*)&vTb[(size_t)(i * 16 + v_dim) * KEYS
                                          + wcur * NDIM + v_kg * 8];
    }

    for (int ci = 0; ci < nChunks; ci++) {
        __syncthreads();   // prev chunk's LDS reads complete
        #pragma unroll
        for (int i = 0; i < 4; i++)
            *(uint4*)&Ks[i * 32 + k_key][(k_dg ^ (k_key & 7)) * 8] = kreg[i];
        #pragma unroll
        for (int i = 0; i < 4; i++)
            *(uint4*)&Vs[i * 16 + v_dim][(v_kg ^ v_dim) * 8] = vreg[i];

        if (ci + 1 < nChunks) {   // prefetch next chunk into regs
            int wn, m0n;
            if ((ci & 1) == 0) { wn = wcur; m0n = 128; }
            else {
                unsigned r2 = rem2 & (rem2 - 1);
                wn = __builtin_ffs((int)r2) - 1; m0n = 0;
            }
            const unsigned short* kb =
                qkv + (size_t)((b * VDIM + wn) * NDIM + m0n) * C3 + CDIM + h * DHE;
            #pragma unroll
            for (int i = 0; i < 4; i++)
                kreg[i] = *(const uint4*)&kb[(size_t)(i * 32 + k_key) * C3 + k_dg * 8];
            #pragma unroll
            for (int i = 0; i < 4; i++)
                vreg[i] = *(const uint4*)&vTb[(size_t)(i * 16 + v_dim) * KEYS
                                              + wn * NDIM + m0n + v_kg * 8];
        }
        __syncthreads();   // LDS tiles visible

        // two 64-key halves: S^T tiles -> packed Ps, then PV for that half
        #pragma unroll
        for (int hk = 0; hk < 2; hk++) {
            #pragma unroll
            for (int kt = 0; kt < 4; kt++) {
                const int nt = hk * 4 + kt;
                // A-frag = K (lane m = key within tile)
                const short8 bk0 = *(const short8*)&Ks[nt * 16 + m][(quad ^ (m & 7)) * 8];
                const short8 bk1 = *(const short8*)&Ks[nt * 16 + m][((4 + quad) ^ (m & 7)) * 8];
                #pragma unroll
                for (int qt = 0; qt < 2; qt++) {
                    float4v s = {};
                    s = __builtin_amdgcn_mfma_f32_16x16x32_bf16(bk0, aq[qt][0], s, 0, 0, 0);
                    s = __builtin_amdgcn_mfma_f32_16x16x32_bf16(bk1, aq[qt][1], s, 0, 0, 0);
                    // s[r]: key = nt*16 + quad*4 + r, query = qt*16 + m
                    const float p0 = __builtin_amdgcn_exp2f(s[0] * c1);
                    const float p1 = __builtin_amdgcn_exp2f(s[1] * c1);
                    const float p2 = __builtin_amdgcn_exp2f(s[2] * c1);
                    const float p3 = __builtin_amdgcn_exp2f(s[3] * c1);
                    rs[qt] += (p0 + p1) + (p2 + p3);
                    uint2 pw;
                    pw.x = pk2(p0, p1);
                    pw.y = pk2(p2, p3);
                    *(uint2*)&Ps[wave][qt * 16 + m][kt * 16 + quad * 4] = pw;
                }
            }
            #pragma unroll
            for (int kk = 0; kk < 2; kk++) {
                const short8 ap0 = *(const short8*)&Ps[wave][m][kk * 32 + quad * 8];
                const short8 ap1 = *(const short8*)&Ps[wave][16 + m][kk * 32 + quad * 8];
                #pragma unroll
                for (int ct = 0; ct < 4; ct++) {
                    const short8 bv = *(const short8*)&Vs[ct * 16 + m]
                        [((hk * 8 + kk * 4 + quad) ^ m) * 8];
                    O[0][ct] = __builtin_amdgcn_mfma_f32_16x16x32_bf16(ap0, bv, O[0][ct], 0, 0, 0);
                    O[1][ct] = __builtin_amdgcn_mfma_f32_16x16x32_bf16(ap1, bv, O[1][ct], 0, 0, 0);
                }
            }
        }
        if (ci & 1) { rem2 &= rem2 - 1; wcur = __builtin_ffs((int)rem2) - 1; }
    }

    // final: reduce l across the 4 quad-copies, broadcast to O rows, write
    #pragma unroll
    for (int qt = 0; qt < 2; qt++) {
        float x = rs[qt];
        x += __shfl_xor(x, 16, 64);
        x += __shfl_xor(x, 32, 64);
        const float inv = (x > 0.f) ? 1.f / x : 0.f;   // query = qt*16 + m
        float invq[4];
        #pragma unroll
        for (int r = 0; r < 4; r++)
            invq[r] = __shfl(inv, quad * 4 + r, 64);   // query = qt*16+quad*4+r
        const size_t rowg = (size_t)((b * VDIM + v) * NDIM) + n0 + qt * 16 + quad * 4;
        #pragma unroll
        for (int ct = 0; ct < 4; ct++)
            #pragma unroll
            for (int r = 0; r < 4; r++)
                ctx[(rowg + r) * CDIM + h * DHE + ct * 16 + m] = f2bf(O[qt][ct][r] * invq[r]);
    }
}

// ---------------------------------------------------------------------------
// Out-proj GEMM, global_load_lds staging; fp32 out + passthrough.
// ---------------------------------------------------------------------------
__global__ __launch_bounds__(256) void gemm_out_mfma(
    const unsigned short* __restrict__ A,   // ctx_b [8192][768] bf16
    const unsigned short* __restrict__ W,   // w_out bf16 [768][768]
    const float* __restrict__ bias,
    const float* __restrict__ feats,
    const int* __restrict__ is_ref,
    float* __restrict__ out)                // [8192][768] fp32
{
    __shared__ __attribute__((aligned(16))) unsigned short As[128][32];
    __shared__ __attribute__((aligned(16))) unsigned short Ws[128][32];
    const int t = threadIdx.x;
    const int wave = t >> 6, lane = t & 63;
    const int m = lane & 15, quad = lane >> 4;
    const int wr = (wave >> 1) * 64, wc = (wave & 1) * 64;
    const int row0 = blockIdx.y * 128, col0 = blockIdx.x * 128;

    const int sr = t >> 2, sk = (t & 3) * 8;
    const unsigned short* ag = &A[(size_t)(row0 + sr) * CDIM + sk];
    const unsigned short* wg = &W[(size_t)(col0 + sr) * CDIM + sk];
    unsigned short* la0 = &As[sr][sk];
    unsigned short* la1 = &As[64 + sr][sk];
    unsigned short* lw0 = &Ws[sr][sk];
    unsigned short* lw1 = &Ws[64 + sr][sk];

    float4v acc[4][4] = {};

    for (int k0 = 0; k0 < CDIM; k0 += 32) {
        gld_lds16(ag + k0, la0);
        gld_lds16(ag + (size_t)64 * CDIM + k0, la1);
        gld_lds16(wg + k0, lw0);
        gld_lds16(wg + (size_t)64 * CDIM + k0, lw1);
        __syncthreads();
        short8 a[4], b[4];
        #pragma unroll
        for (int rt = 0; rt < 4; rt++)
            a[rt] = *(const short8*)&As[wr + rt * 16 + m][quad * 8];
        #pragma unroll
        for (int ct = 0; ct < 4; ct++)
            b[ct] = *(const short8*)&Ws[wc + ct * 16 + m][quad * 8];
        #pragma unroll
        for (int rt = 0; rt < 4; rt++)
            #pragma unroll
            for (int ct = 0; ct < 4; ct++)
                acc[rt][ct] = __builtin_amdgcn_mfma_f32_16x16x32_bf16(
                    a[rt], b[ct], acc[rt][ct], 0, 0, 0);
        __syncthreads();
    }

    const int bidx = row0 / (VDIM * NDIM);
    const int vidx = (row0 / NDIM) % VDIM;
    const int my = is_ref[bidx * VDIM + vidx];
    bool has = false;
    #pragma unroll
    for (int w = 0; w < VDIM; w++) has = has || (is_ref[bidx * VDIM + w] != my);

    #pragma unroll
    for (int ct = 0; ct < 4; ct++) {
        const int col = col0 + wc + ct * 16 + m;
        const float bv = bias[col];
        #pragma unroll
        for (int rt = 0; rt < 4; rt++) {
            const size_t row = (size_t)row0 + wr + rt * 16 + quad * 4;
            #pragma unroll
            for (int r = 0; r < 4; r++) {
                float o = acc[rt][ct][r] + bv;
                if (!has) o = feats[(row + r) * CDIM + col];
                out[(row + r) * CDIM + col] = o;
            }
        }
    }
}

extern "C" void kernel_launch(void* const* d_in, const int* in_sizes, int n_in,
                              void* d_out, int out_size, void* d_ws, size_t ws_size,
                              hipStream_t stream) {
    const float* feats = (const float*)d_in[0];
    const int*   is_ref = (const int*)d_in[1];
    const float* w_qkv = (const float*)d_in[2];
    const float* b_qkv = (const float*)d_in[3];
    const float* w_out = (const float*)d_in[4];
    const float* b_out = (const float*)d_in[5];
    float* out = (float*)d_out;

    unsigned short* qkv_b = (unsigned short*)d_ws;                 // 8192x2304
    unsigned short* vT    = qkv_b + (size_t)ROWS * C3;             // 4x12x64x2048
    unsigned short* ctx_b = vT + (size_t)BDIM * HDIM * DHE * KEYS; // 8192x768
    unsigned short* A_bf  = ctx_b + (size_t)ROWS * CDIM;           // 8192x768
    unsigned short* Wq_bf = A_bf + (size_t)ROWS * CDIM;            // 2304x768
    unsigned short* Wo_bf = Wq_bf + (size_t)C3 * CDIM;             // 768x768

    cast_bf16_all<<<dim3((NA8 + NW8 + NO8) / 256), 256, 0, stream>>>(
        feats, w_qkv, w_out, A_bf, Wq_bf, Wo_bf);

    dim3 g1(C3 / 128, ROWS / 128);                                 // 18 x 64
    gemm_qkv_mfma<<<g1, 256, 0, stream>>>(A_bf, Wq_bf, b_qkv, qkv_b, vT);

    attn_mfma<<<dim3(768), 256, 0, stream>>>(qkv_b, vT, is_ref, ctx_b);

    dim3 g3(CDIM / 128, ROWS / 128);                               // 6 x 64
    gemm_out_mfma<<<g3, 256, 0, stream>>>(ctx_b, Wo_bf, b_out, feats, is_ref, out);
    (void)in_sizes; (void)n_in; (void)out_size; (void)ws_size;
}

// Round 8
// 245.890 us; speedup vs baseline: 1.2956x; 1.0242x over previous
//
#include <hip/hip_runtime.h>
#include <hip/hip_bf16.h>
#include <math.h>

#define BDIM 4
#define VDIM 8
#define NDIM 256
#define CDIM 768
#define HDIM 12
#define DHE  64
#define C3   (3*CDIM)
#define ROWS (BDIM*VDIM*NDIM)
#define KEYS (VDIM*NDIM)   // 2048

typedef __attribute__((ext_vector_type(8))) short short8;   // 8 bf16 = 4 VGPR
typedef __attribute__((ext_vector_type(4))) float float4v;  // MFMA acc

__device__ inline unsigned short f2bf(float f) {
    unsigned int u = __builtin_bit_cast(unsigned int, f);
    u += 0x7fffu + ((u >> 16) & 1u);   // RNE
    return (unsigned short)(u >> 16);
}

// packed f32x2 -> bf16x2 in a uint (low half = a, high half = b), RNE
__device__ __forceinline__ unsigned int pk2(float a, float b) {
    return (unsigned int)f2bf(a) | ((unsigned int)f2bf(b) << 16);
}

// 8 fp32 (two float4) -> uint4 of 8 bf16
__device__ __forceinline__ uint4 pk8(float4 a, float4 b) {
    uint4 r;
    r.x = pk2(a.x, a.y); r.y = pk2(a.z, a.w);
    r.z = pk2(b.x, b.y); r.w = pk2(b.z, b.w);
    return r;
}

// async 16B global -> LDS (wave-uniform base + lane*16; lane-order == LDS order)
__device__ __forceinline__ void gld_lds16(const unsigned short* g, unsigned short* l) {
    __builtin_amdgcn_global_load_lds(
        (const __attribute__((address_space(1))) void*)g,
        (__attribute__((address_space(3))) void*)l, 16, 0, 0);
}

// ---------------------------------------------------------------------------
// One-shot fp32 -> bf16 pre-cast of feats, w_qkv, w_out (memory-bound ~9us).
// ---------------------------------------------------------------------------
#define NA8 786432   // 8192*768/8
#define NW8 221184   // 2304*768/8
#define NO8 73728    //  768*768/8

__global__ __launch_bounds__(256) void cast_bf16_all(
    const float* __restrict__ fA, const float* __restrict__ fW,
    const float* __restrict__ fO,
    unsigned short* __restrict__ bA, unsigned short* __restrict__ bW,
    unsigned short* __restrict__ bO)
{
    const int gid = blockIdx.x * 256 + threadIdx.x;
    const float* src;
    unsigned short* dst;
    int idx;
    if (gid < NA8)            { src = fA; dst = bA; idx = gid; }
    else if (gid < NA8 + NW8) { src = fW; dst = bW; idx = gid - NA8; }
    else                      { src = fO; dst = bO; idx = gid - NA8 - NW8; }
    const float4* p = (const float4*)(src + (size_t)idx * 8);
    *(uint4*)(dst + (size_t)idx * 8) = pk8(p[0], p[1]);
}

// ---------------------------------------------------------------------------
// Fused QKV GEMM, m97 step-3 structure: bf16 inputs, global_load_lds width-16
// direct into linear [128][32] LDS tiles. V col-blocks (col0 >= 1536) write
// the TRANSPOSED vT buffer directly and skip qkv.
// ---------------------------------------------------------------------------
__global__ __launch_bounds__(256) void gemm_qkv_mfma(
    const unsigned short* __restrict__ A,    // feats bf16 [8192][768]
    const unsigned short* __restrict__ W,    // w_qkv bf16 [2304][768]
    const float* __restrict__ bias,
    unsigned short* __restrict__ out,        // qkv [8192][2304] bf16 (Q,K only)
    unsigned short* __restrict__ vT)         // [4][12][64][2048] bf16
{
    __shared__ __attribute__((aligned(16))) unsigned short As[128][32];
    __shared__ __attribute__((aligned(16))) unsigned short Ws[128][32];
    const int t = threadIdx.x;
    const int wave = t >> 6, lane = t & 63;
    const int m = lane & 15, quad = lane >> 4;
    const int wr = (wave >> 1) * 64, wc = (wave & 1) * 64;
    const int row0 = blockIdx.y * 128, col0 = blockIdx.x * 128;

    // staging: thread t owns row (t>>2), k-chunk (t&3)*8 -> LDS byte t*16
    const int sr = t >> 2, sk = (t & 3) * 8;
    const unsigned short* ag = &A[(size_t)(row0 + sr) * CDIM + sk];
    const unsigned short* wg = &W[(size_t)(col0 + sr) * CDIM + sk];
    unsigned short* la0 = &As[sr][sk];
    unsigned short* la1 = &As[64 + sr][sk];
    unsigned short* lw0 = &Ws[sr][sk];
    unsigned short* lw1 = &Ws[64 + sr][sk];

    float4v acc[4][4] = {};

    for (int k0 = 0; k0 < CDIM; k0 += 32) {
        gld_lds16(ag + k0, la0);
        gld_lds16(ag + (size_t)64 * CDIM + k0, la1);
        gld_lds16(wg + k0, lw0);
        gld_lds16(wg + (size_t)64 * CDIM + k0, lw1);
        __syncthreads();
        short8 a[4], b[4];
        #pragma unroll
        for (int rt = 0; rt < 4; rt++)
            a[rt] = *(const short8*)&As[wr + rt * 16 + m][quad * 8];
        #pragma unroll
        for (int ct = 0; ct < 4; ct++)
            b[ct] = *(const short8*)&Ws[wc + ct * 16 + m][quad * 8];
        #pragma unroll
        for (int rt = 0; rt < 4; rt++)
            #pragma unroll
            for (int ct = 0; ct < 4; ct++)
                acc[rt][ct] = __builtin_amdgcn_mfma_f32_16x16x32_bf16(
                    a[rt], b[ct], acc[rt][ct], 0, 0, 0);
        __syncthreads();
    }

    if (col0 < 2 * CDIM) {
        // Q/K epilogue -> qkv
        #pragma unroll
        for (int ct = 0; ct < 4; ct++) {
            const int col = col0 + wc + ct * 16 + m;
            const float bv = bias[col];
            #pragma unroll
            for (int rt = 0; rt < 4; rt++) {
                const size_t row = (size_t)row0 + wr + rt * 16 + quad * 4;
                #pragma unroll
                for (int r = 0; r < 4; r++)
                    out[(row + r) * C3 + col] = f2bf(acc[rt][ct][r] + bv);
            }
        }
    } else {
        // V epilogue -> transposed vT (4 consecutive keys per lane -> 8B)
        #pragma unroll
        for (int ct = 0; ct < 4; ct++) {
            const int vcol = col0 + wc + ct * 16 + m - 2 * CDIM;
            const int h = vcol >> 6, d = vcol & 63;
            const float bv = bias[col0 + wc + ct * 16 + m];
            #pragma unroll
            for (int rt = 0; rt < 4; rt++) {
                const int row = row0 + wr + rt * 16 + quad * 4;
                const int bidx = row >> 11, key = row & 2047;
                ushort4 pkv;
                pkv.x = f2bf(acc[rt][ct][0] + bv);
                pkv.y = f2bf(acc[rt][ct][1] + bv);
                pkv.z = f2bf(acc[rt][ct][2] + bv);
                pkv.w = f2bf(acc[rt][ct][3] + bv);
                *(ushort4*)&vT[((size_t)(bidx * HDIM + h) * DHE + d) * KEYS + key] = pkv;
            }
        }
    }
}

// ---------------------------------------------------------------------------
// MFMA flash attention. R8: XCD-LOCAL LPT — combine R2's locality (FETCH
// 59 MB, grp pinned to one XCD's L2) with R7's balance (occ 29%). Evidence:
// each alone gave ~97/96us; mechanisms are independent (placement vs order).
// Construction (analytic, wave-uniform, ~250 ops):
//   1. sort 4 batches desc by weight r*(8-r) (grp work depends only on b)
//   2. snake-deal the 48 (b,h) grps into 8 XCDs x 6 grps  -> balanced
//      per-XCD sums, each grp's K/V (~770KB) pinned to one XCD L2
//   3. within the XCD, walk its 96 tasks (grp,half,v) in descending
//      length-class order, snake over 32 CUs x 3 rounds (per-XCD LPT)
// Block g -> (xcd=g%8, cu=(g/8)%32, round=g/256) -> task, closed form.
// Inner loop = R2/R7 known-best structure, unchanged.
// ---------------------------------------------------------------------------
__global__ __launch_bounds__(256, 3) void attn_mfma(
    const unsigned short* __restrict__ qkv,  // [8192][2304] bf16 (Q,K)
    const unsigned short* __restrict__ vT,   // [4][12][64][2048] bf16
    const int* __restrict__ is_ref,
    unsigned short* __restrict__ ctx)        // [8192][768] bf16
{
    const int g = blockIdx.x;
    const int myx = g & 7, cuu = (g >> 3) & 31, round = g >> 8;
    const int j = round * 32 + ((round & 1) ? (31 - cuu) : cuu); // slot 0..95

    // ---- per-batch ref info ----
    int rmask[4], r4[4];
    #pragma unroll
    for (int bb = 0; bb < 4; bb++) {
        int mask = 0;
        #pragma unroll
        for (int w = 0; w < VDIM; w++)
            if (is_ref[bb * VDIM + w] != 0) mask |= 1 << w;
        rmask[bb] = mask; r4[bb] = __popc(mask);
    }
    // ---- 1. sort batches desc by weight r(8-r) (bubble, deterministic) ----
    int ord[4] = {0, 1, 2, 3};
    #pragma unroll
    for (int i = 0; i < 3; i++)
        #pragma unroll
        for (int k = 0; k < 3 - i; k++) {
            const int wa = r4[ord[k]] * (8 - r4[ord[k]]);
            const int wb = r4[ord[k + 1]] * (8 - r4[ord[k + 1]]);
            if (wb > wa) { int tmp = ord[k]; ord[k] = ord[k + 1]; ord[k + 1] = tmp; }
        }
    // ---- 2. snake-deal 48 grps to 8 XCDs; collect my 6 (Gb, Gh) ----
    int Gb[6], Gh[6], ng = 0;
    for (int p = 0; p < 48; p++) {
        const int row = p >> 3, col = p & 7;
        const int x = (row & 1) ? (7 - col) : col;
        if (x == myx) { Gb[ng] = ord[p / 12]; Gh[ng] = p % 12; ng++; }
    }
    // ---- 3. class walk: find j-th task of this XCD (LPT order) ----
    int b = 0, h = 0, half = 0, v = 0, Lsel = 0;
    {
        int jj = j;
        bool found = false;
        for (int o = 8; o >= 0 && !found; o--) {
            for (int gi = 0; gi < 6 && !found; gi++) {
                const int b2 = Gb[gi], r2 = r4[b2];
                const int nv_o = ((8 - r2) == o ? r2 : 0) + (r2 == o ? (8 - r2) : 0);
                const int cnt = 2 * nv_o;
                if (cnt > 0 && jj < cnt) {
                    b = b2; h = Gh[gi]; Lsel = o;
                    half = jj / nv_o;
                    int pos = jj % nv_o;
                    int S = (((8 - r2) == o) ? rmask[b2] : 0)
                          | ((r2 == o) ? ((~rmask[b2]) & 0xff) : 0);
                    for (int vv = 0; vv < 8; vv++)
                        if ((S >> vv) & 1) { if (pos == 0) { v = vv; break; } pos--; }
                    found = true;
                } else jj -= cnt;
            }
        }
    }
    // ------------------------------------------------------

    const int t = threadIdx.x, wave = t >> 6, lane = t & 63;
    const int m = lane & 15, quad = lane >> 4;
    const int n0 = half * 128 + wave * 32;

    __shared__ unsigned short Ks[128][64];   // [key][dim], dg' = dg ^ (key&7)
    __shared__ unsigned short Vs[64][128];   // [dim][key], kg' = kg ^ (dim&15)
    __shared__ unsigned short Ps[4][32][72]; // [wave][query][64-key half]

    const int my_ref = (rmask[b] >> v) & 1;
    const unsigned amask = my_ref ? (unsigned)((~rmask[b]) & 0xff)
                                  : (unsigned)rmask[b];
    const int nChunks = 2 * Lsel;

    const float c1 = 0.18033688f;  // 0.125 * log2(e)

    // Q B-frags: B[n=query=m][k=quad*8+j], two 32-dim K-steps
    short8 aq[2][2];
    #pragma unroll
    for (int qt = 0; qt < 2; qt++) {
        const size_t row = (size_t)((b * VDIM + v) * NDIM) + n0 + qt * 16 + m;
        #pragma unroll
        for (int ks = 0; ks < 2; ks++)
            aq[qt][ks] = *(const short8*)&qkv[row * C3 + h * DHE + ks * 32 + quad * 8];
    }

    float rs[2] = {0.f, 0.f};     // per-lane l partial, query = qt*16 + m
    float4v O[2][4] = {};

    // staging thread coords
    const int k_key = t >> 3, k_dg = t & 7;    // key = i*32 + k_key
    const int v_dim = t >> 4, v_kg = t & 15;   // dim = i*16 + v_dim

    const unsigned short* vTb = vT + (size_t)(b * HDIM + h) * DHE * KEYS;

    uint4 kreg[4], vreg[4];
    unsigned rem2 = amask;
    int wcur = __builtin_ffs((int)rem2) - 1;

    if (nChunks > 0) {
        const unsigned short* kb =
            qkv + (size_t)((b * VDIM + wcur) * NDIM) * C3 + CDIM + h * DHE;
        #pragma unroll
        for (int i = 0; i < 4; i++)
            kreg[i] = *(const uint4*)&kb[(size_t)(i * 32 + k_key) * C3 + k_dg * 8];
        #pragma unroll
        for (int i = 0; i < 4; i++)
            vreg[i] = *(const uint4*)&vTb[(size_t)(i * 16 + v_dim) * KEYS
                                          + wcur * NDIM + v_kg * 8];
    }

    for (int ci = 0; ci < nChunks; ci++) {
        __syncthreads();   // prev chunk's LDS reads complete
        #pragma unroll
        for (int i = 0; i < 4; i++)
            *(uint4*)&Ks[i * 32 + k_key][(k_dg ^ (k_key & 7)) * 8] = kreg[i];
        #pragma unroll
        for (int i = 0; i < 4; i++)
            *(uint4*)&Vs[i * 16 + v_dim][(v_kg ^ v_dim) * 8] = vreg[i];

        if (ci + 1 < nChunks) {   // prefetch next chunk into regs
            int wn, m0n;
            if ((ci & 1) == 0) { wn = wcur; m0n = 128; }
            else {
                unsigned r2 = rem2 & (rem2 - 1);
                wn = __builtin_ffs((int)r2) - 1; m0n = 0;
            }
            const unsigned short* kb =
                qkv + (size_t)((b * VDIM + wn) * NDIM + m0n) * C3 + CDIM + h * DHE;
            #pragma unroll
            for (int i = 0; i < 4; i++)
                kreg[i] = *(const uint4*)&kb[(size_t)(i * 32 + k_key) * C3 + k_dg * 8];
            #pragma unroll
            for (int i = 0; i < 4; i++)
                vreg[i] = *(const uint4*)&vTb[(size_t)(i * 16 + v_dim) * KEYS
                                              + wn * NDIM + m0n + v_kg * 8];
        }
        __syncthreads();   // LDS tiles visible

        // two 64-key halves: S^T tiles -> packed Ps, then PV for that half
        #pragma unroll
        for (int hk = 0; hk < 2; hk++) {
            #pragma unroll
            for (int kt = 0; kt < 4; kt++) {
                const int nt = hk * 4 + kt;
                // A-frag = K (lane m = key within tile)
                const short8 bk0 = *(const short8*)&Ks[nt * 16 + m][(quad ^ (m & 7)) * 8];
                const short8 bk1 = *(const short8*)&Ks[nt * 16 + m][((4 + quad) ^ (m & 7)) * 8];
                #pragma unroll
                for (int qt = 0; qt < 2; qt++) {
                    float4v s = {};
                    s = __builtin_amdgcn_mfma_f32_16x16x32_bf16(bk0, aq[qt][0], s, 0, 0, 0);
                    s = __builtin_amdgcn_mfma_f32_16x16x32_bf16(bk1, aq[qt][1], s, 0, 0, 0);
                    // s[r]: key = nt*16 + quad*4 + r, query = qt*16 + m
                    const float p0 = __builtin_amdgcn_exp2f(s[0] * c1);
                    const float p1 = __builtin_amdgcn_exp2f(s[1] * c1);
                    const float p2 = __builtin_amdgcn_exp2f(s[2] * c1);
                    const float p3 = __builtin_amdgcn_exp2f(s[3] * c1);
                    rs[qt] += (p0 + p1) + (p2 + p3);
                    uint2 pw;
                    pw.x = pk2(p0, p1);
                    pw.y = pk2(p2, p3);
                    *(uint2*)&Ps[wave][qt * 16 + m][kt * 16 + quad * 4] = pw;
                }
            }
            #pragma unroll
            for (int kk = 0; kk < 2; kk++) {
                const short8 ap0 = *(const short8*)&Ps[wave][m][kk * 32 + quad * 8];
                const short8 ap1 = *(const short8*)&Ps[wave][16 + m][kk * 32 + quad * 8];
                #pragma unroll
                for (int ct = 0; ct < 4; ct++) {
                    const short8 bv = *(const short8*)&Vs[ct * 16 + m]
                        [((hk * 8 + kk * 4 + quad) ^ m) * 8];
                    O[0][ct] = __builtin_amdgcn_mfma_f32_16x16x32_bf16(ap0, bv, O[0][ct], 0, 0, 0);
                    O[1][ct] = __builtin_amdgcn_mfma_f32_16x16x32_bf16(ap1, bv, O[1][ct], 0, 0, 0);
                }
            }
        }
        if (ci & 1) { rem2 &= rem2 - 1; wcur = __builtin_ffs((int)rem2) - 1; }
    }

    // final: reduce l across the 4 quad-copies, broadcast to O rows, write
    #pragma unroll
    for (int qt = 0; qt < 2; qt++) {
        float x = rs[qt];
        x += __shfl_xor(x, 16, 64);
        x += __shfl_xor(x, 32, 64);
        const float inv = (x > 0.f) ? 1.f / x : 0.f;   // query = qt*16 + m
        float invq[4];
        #pragma unroll
        for (int r = 0; r < 4; r++)
            invq[r] = __shfl(inv, quad * 4 + r, 64);   // query = qt*16+quad*4+r
        const size_t rowg = (size_t)((b * VDIM + v) * NDIM) + n0 + qt * 16 + quad * 4;
        #pragma unroll
        for (int ct = 0; ct < 4; ct++)
            #pragma unroll
            for (int r = 0; r < 4; r++)
                ctx[(rowg + r) * CDIM + h * DHE + ct * 16 + m] = f2bf(O[qt][ct][r] * invq[r]);
    }
}

// ---------------------------------------------------------------------------
// Out-proj GEMM, global_load_lds staging; fp32 out + passthrough.
// ---------------------------------------------------------------------------
__global__ __launch_bounds__(256) void gemm_out_mfma(
    const unsigned short* __restrict__ A,   // ctx_b [8192][768] bf16
    const unsigned short* __restrict__ W,   // w_out bf16 [768][768]
    const float* __restrict__ bias,
    const float* __restrict__ feats,
    const int* __restrict__ is_ref,
    float* __restrict__ out)                // [8192][768] fp32
{
    __shared__ __attribute__((aligned(16))) unsigned short As[128][32];
    __shared__ __attribute__((aligned(16))) unsigned short Ws[128][32];
    const int t = threadIdx.x;
    const int wave = t >> 6, lane = t & 63;
    const int m = lane & 15, quad = lane >> 4;
    const int wr = (wave >> 1) * 64, wc = (wave & 1) * 64;
    const int row0 = blockIdx.y * 128, col0 = blockIdx.x * 128;

    const int sr = t >> 2, sk = (t & 3) * 8;
    const unsigned short* ag = &A[(size_t)(row0 + sr) * CDIM + sk];
    const unsigned short* wg = &W[(size_t)(col0 + sr) * CDIM + sk];
    unsigned short* la0 = &As[sr][sk];
    unsigned short* la1 = &As[64 + sr][sk];
    unsigned short* lw0 = &Ws[sr][sk];
    unsigned short* lw1 = &Ws[64 + sr][sk];

    float4v acc[4][4] = {};

    for (int k0 = 0; k0 < CDIM; k0 += 32) {
        gld_lds16(ag + k0, la0);
        gld_lds16(ag + (size_t)64 * CDIM + k0, la1);
        gld_lds16(wg + k0, lw0);
        gld_lds16(wg + (size_t)64 * CDIM + k0, lw1);
        __syncthreads();
        short8 a[4], b[4];
        #pragma unroll
        for (int rt = 0; rt < 4; rt++)
            a[rt] = *(const short8*)&As[wr + rt * 16 + m][quad * 8];
        #pragma unroll
        for (int ct = 0; ct < 4; ct++)
            b[ct] = *(const short8*)&Ws[wc + ct * 16 + m][quad * 8];
        #pragma unroll
        for (int rt = 0; rt < 4; rt++)
            #pragma unroll
            for (int ct = 0; ct < 4; ct++)
                acc[rt][ct] = __builtin_amdgcn_mfma_f32_16x16x32_bf16(
                    a[rt], b[ct], acc[rt][ct], 0, 0, 0);
        __syncthreads();
    }

    const int bidx = row0 / (VDIM * NDIM);
    const int vidx = (row0 / NDIM) % VDIM;
    const int my = is_ref[bidx * VDIM + vidx];
    bool has = false;
    #pragma unroll
    for (int w = 0; w < VDIM; w++) has = has || (is_ref[bidx * VDIM + w] != my);

    #pragma unroll
    for (int ct = 0; ct < 4; ct++) {
        const int col = col0 + wc + ct * 16 + m;
        const float bv = bias[col];
        #pragma unroll
        for (int rt = 0; rt < 4; rt++) {
            const size_t row = (size_t)row0 + wr + rt * 16 + quad * 4;
            #pragma unroll
            for (int r = 0; r < 4; r++) {
                float o = acc[rt][ct][r] + bv;
                if (!has) o = feats[(row + r) * CDIM + col];
                out[(row + r) * CDIM + col] = o;
            }
        }
    }
}

extern "C" void kernel_launch(void* const* d_in, const int* in_sizes, int n_in,
                              void* d_out, int out_size, void* d_ws, size_t ws_size,
                              hipStream_t stream) {
    const float* feats = (const float*)d_in[0];
    const int*   is_ref = (const int*)d_in[1];
    const float* w_qkv = (const float*)d_in[2];
    const float* b_qkv = (const float*)d_in[3];
    const float* w_out = (const float*)d_in[4];
    const float* b_out = (const float*)d_in[5];
    float* out = (float*)d_out;

    unsigned short* qkv_b = (unsigned short*)d_ws;                 // 8192x2304
    unsigned short* vT    = qkv_b + (size_t)ROWS * C3;             // 4x12x64x2048
    unsigned short* ctx_b = vT + (size_t)BDIM * HDIM * DHE * KEYS; // 8192x768
    unsigned short* A_bf  = ctx_b + (size_t)ROWS * CDIM;           // 8192x768
    unsigned short* Wq_bf = A_bf + (size_t)ROWS * CDIM;            // 2304x768
    unsigned short* Wo_bf = Wq_bf + (size_t)C3 * CDIM;             // 768x768

    cast_bf16_all<<<dim3((NA8 + NW8 + NO8) / 256), 256, 0, stream>>>(
        feats, w_qkv, w_out, A_bf, Wq_bf, Wo_bf);

    dim3 g1(C3 / 128, ROWS / 128);                                 // 18 x 64
    gemm_qkv_mfma<<<g1, 256, 0, stream>>>(A_bf, Wq_bf, b_qkv, qkv_b, vT);

    attn_mfma<<<dim3(768), 256, 0, stream>>>(qkv_b, vT, is_ref, ctx_b);

    dim3 g3(CDIM / 128, ROWS / 128);                               // 6 x 64
    gemm_out_mfma<<<g3, 256, 0, stream>>>(ctx_b, Wo_bf, b_out, feats, is_ref, out);
    (void)in_sizes; (void)n_in; (void)out_size; (void)ws_size;
}

// Round 9
// 244.144 us; speedup vs baseline: 1.3049x; 1.0072x over previous
//
#include <hip/hip_runtime.h>
#include <hip/hip_bf16.h>
#include <math.h>

#define BDIM 4
#define VDIM 8
#define NDIM 256
#define CDIM 768
#define HDIM 12
#define DHE  64
#define C3   (3*CDIM)
#define ROWS (BDIM*VDIM*NDIM)
#define KEYS (VDIM*NDIM)   // 2048

typedef __attribute__((ext_vector_type(8))) short short8;   // 8 bf16 = 4 VGPR
typedef __attribute__((ext_vector_type(4))) float float4v;  // MFMA acc

__device__ inline unsigned short f2bf(float f) {
    unsigned int u = __builtin_bit_cast(unsigned int, f);
    u += 0x7fffu + ((u >> 16) & 1u);   // RNE
    return (unsigned short)(u >> 16);
}

// packed f32x2 -> bf16x2 in a uint (low half = a, high half = b), RNE
__device__ __forceinline__ unsigned int pk2(float a, float b) {
    return (unsigned int)f2bf(a) | ((unsigned int)f2bf(b) << 16);
}

// 8 fp32 (two float4) -> uint4 of 8 bf16
__device__ __forceinline__ uint4 pk8(float4 a, float4 b) {
    uint4 r;
    r.x = pk2(a.x, a.y); r.y = pk2(a.z, a.w);
    r.z = pk2(b.x, b.y); r.w = pk2(b.z, b.w);
    return r;
}

// async 16B global -> LDS (wave-uniform base + lane*16; lane-order == LDS order)
__device__ __forceinline__ void gld_lds16(const unsigned short* g, unsigned short* l) {
    __builtin_amdgcn_global_load_lds(
        (const __attribute__((address_space(1))) void*)g,
        (__attribute__((address_space(3))) void*)l, 16, 0, 0);
}

// ---------------------------------------------------------------------------
// One-shot fp32 -> bf16 pre-cast of feats, w_qkv, w_out (memory-bound ~9us).
// ---------------------------------------------------------------------------
#define NA8 786432   // 8192*768/8
#define NW8 221184   // 2304*768/8
#define NO8 73728    //  768*768/8

__global__ __launch_bounds__(256) void cast_bf16_all(
    const float* __restrict__ fA, const float* __restrict__ fW,
    const float* __restrict__ fO,
    unsigned short* __restrict__ bA, unsigned short* __restrict__ bW,
    unsigned short* __restrict__ bO)
{
    const int gid = blockIdx.x * 256 + threadIdx.x;
    const float* src;
    unsigned short* dst;
    int idx;
    if (gid < NA8)            { src = fA; dst = bA; idx = gid; }
    else if (gid < NA8 + NW8) { src = fW; dst = bW; idx = gid - NA8; }
    else                      { src = fO; dst = bO; idx = gid - NA8 - NW8; }
    const float4* p = (const float4*)(src + (size_t)idx * 8);
    *(uint4*)(dst + (size_t)idx * 8) = pk8(p[0], p[1]);
}

// ---------------------------------------------------------------------------
// Fused QKV GEMM, m97 step-3 structure + R9 XCD-chunked swizzle (T1):
// nwg=1152, 144/XCD = 8 row-panels x 18 col-blocks -> per-XCD L2 holds its
// 1.57MB A-slab + 3.54MB W; W re-reads become L2-local.
// ---------------------------------------------------------------------------
__global__ __launch_bounds__(256) void gemm_qkv_mfma(
    const unsigned short* __restrict__ A,    // feats bf16 [8192][768]
    const unsigned short* __restrict__ W,    // w_qkv bf16 [2304][768]
    const float* __restrict__ bias,
    unsigned short* __restrict__ out,        // qkv [8192][2304] bf16 (Q,K only)
    unsigned short* __restrict__ vT)         // [4][12][64][2048] bf16
{
    __shared__ __attribute__((aligned(16))) unsigned short As[128][32];
    __shared__ __attribute__((aligned(16))) unsigned short Ws[128][32];
    const int t = threadIdx.x;
    const int wave = t >> 6, lane = t & 63;
    const int m = lane & 15, quad = lane >> 4;
    const int wr = (wave >> 1) * 64, wc = (wave & 1) * 64;

    const int lin = blockIdx.y * gridDim.x + blockIdx.x;
    const int cpx = (gridDim.x * gridDim.y) >> 3;
    const int swz = (lin & 7) * cpx + (lin >> 3);
    const int row0 = (swz / gridDim.x) * 128, col0 = (swz % gridDim.x) * 128;

    // staging: thread t owns row (t>>2), k-chunk (t&3)*8 -> LDS byte t*16
    const int sr = t >> 2, sk = (t & 3) * 8;
    const unsigned short* ag = &A[(size_t)(row0 + sr) * CDIM + sk];
    const unsigned short* wg = &W[(size_t)(col0 + sr) * CDIM + sk];
    unsigned short* la0 = &As[sr][sk];
    unsigned short* la1 = &As[64 + sr][sk];
    unsigned short* lw0 = &Ws[sr][sk];
    unsigned short* lw1 = &Ws[64 + sr][sk];

    float4v acc[4][4] = {};

    for (int k0 = 0; k0 < CDIM; k0 += 32) {
        gld_lds16(ag + k0, la0);
        gld_lds16(ag + (size_t)64 * CDIM + k0, la1);
        gld_lds16(wg + k0, lw0);
        gld_lds16(wg + (size_t)64 * CDIM + k0, lw1);
        __syncthreads();
        short8 a[4], b[4];
        #pragma unroll
        for (int rt = 0; rt < 4; rt++)
            a[rt] = *(const short8*)&As[wr + rt * 16 + m][quad * 8];
        #pragma unroll
        for (int ct = 0; ct < 4; ct++)
            b[ct] = *(const short8*)&Ws[wc + ct * 16 + m][quad * 8];
        #pragma unroll
        for (int rt = 0; rt < 4; rt++)
            #pragma unroll
            for (int ct = 0; ct < 4; ct++)
                acc[rt][ct] = __builtin_amdgcn_mfma_f32_16x16x32_bf16(
                    a[rt], b[ct], acc[rt][ct], 0, 0, 0);
        __syncthreads();
    }

    if (col0 < 2 * CDIM) {
        // Q/K epilogue -> qkv
        #pragma unroll
        for (int ct = 0; ct < 4; ct++) {
            const int col = col0 + wc + ct * 16 + m;
            const float bv = bias[col];
            #pragma unroll
            for (int rt = 0; rt < 4; rt++) {
                const size_t row = (size_t)row0 + wr + rt * 16 + quad * 4;
                #pragma unroll
                for (int r = 0; r < 4; r++)
                    out[(row + r) * C3 + col] = f2bf(acc[rt][ct][r] + bv);
            }
        }
    } else {
        // V epilogue -> transposed vT (4 consecutive keys per lane -> 8B)
        #pragma unroll
        for (int ct = 0; ct < 4; ct++) {
            const int vcol = col0 + wc + ct * 16 + m - 2 * CDIM;
            const int h = vcol >> 6, d = vcol & 63;
            const float bv = bias[col0 + wc + ct * 16 + m];
            #pragma unroll
            for (int rt = 0; rt < 4; rt++) {
                const int row = row0 + wr + rt * 16 + quad * 4;
                const int bidx = row >> 11, key = row & 2047;
                ushort4 pkv;
                pkv.x = f2bf(acc[rt][ct][0] + bv);
                pkv.y = f2bf(acc[rt][ct][1] + bv);
                pkv.z = f2bf(acc[rt][ct][2] + bv);
                pkv.w = f2bf(acc[rt][ct][3] + bv);
                *(ushort4*)&vT[((size_t)(bidx * HDIM + h) * DHE + d) * KEYS + key] = pkv;
            }
        }
    }
}

// ---------------------------------------------------------------------------
// MFMA flash attention. R9: Ps LDS ELIMINATED — P redistributed in registers.
// After S^T, lane (m=query,quad) holds keys kt*16+quad*4+{0..3} as uint2
// pq[qt][kt]. PV A-frag for lane (m,quad) = keys kk*32+quad*8+{0..7} =
// pq[qt][nt] of lanes (m, 2*(quad&1)) and (m, 2*(quad&1)+1), nt=kk*2+(quad>>1).
// Pull via uniform-register __shfl of both nt candidates + cndmask select.
// Removes per chunk: 16 ds_write_b64 + 8 ds_read_b128 + write->read lgkm
// round-trip + the Ps bank conflicts; LDS 51.2K -> 32.8K.
// Scheduler = R8 XCD-local LPT (FETCH 37MB, occ 26%), unchanged.
// ---------------------------------------------------------------------------
__global__ __launch_bounds__(256, 3) void attn_mfma(
    const unsigned short* __restrict__ qkv,  // [8192][2304] bf16 (Q,K)
    const unsigned short* __restrict__ vT,   // [4][12][64][2048] bf16
    const int* __restrict__ is_ref,
    unsigned short* __restrict__ ctx)        // [8192][768] bf16
{
    const int g = blockIdx.x;
    const int myx = g & 7, cuu = (g >> 3) & 31, round = g >> 8;
    const int j = round * 32 + ((round & 1) ? (31 - cuu) : cuu); // slot 0..95

    // ---- per-batch ref info ----
    int rmask[4], r4[4];
    #pragma unroll
    for (int bb = 0; bb < 4; bb++) {
        int mask = 0;
        #pragma unroll
        for (int w = 0; w < VDIM; w++)
            if (is_ref[bb * VDIM + w] != 0) mask |= 1 << w;
        rmask[bb] = mask; r4[bb] = __popc(mask);
    }
    // ---- 1. sort batches desc by weight r(8-r) ----
    int ord[4] = {0, 1, 2, 3};
    #pragma unroll
    for (int i = 0; i < 3; i++)
        #pragma unroll
        for (int k = 0; k < 3 - i; k++) {
            const int wa = r4[ord[k]] * (8 - r4[ord[k]]);
            const int wb = r4[ord[k + 1]] * (8 - r4[ord[k + 1]]);
            if (wb > wa) { int tmp = ord[k]; ord[k] = ord[k + 1]; ord[k + 1] = tmp; }
        }
    // ---- 2. snake-deal 48 grps to 8 XCDs; collect my 6 (Gb, Gh) ----
    int Gb[6], Gh[6], ng = 0;
    for (int p = 0; p < 48; p++) {
        const int row = p >> 3, col = p & 7;
        const int x = (row & 1) ? (7 - col) : col;
        if (x == myx) { Gb[ng] = ord[p / 12]; Gh[ng] = p % 12; ng++; }
    }
    // ---- 3. class walk: find j-th task of this XCD (LPT order) ----
    int b = 0, h = 0, half = 0, v = 0, Lsel = 0;
    {
        int jj = j;
        bool found = false;
        for (int o = 8; o >= 0 && !found; o--) {
            for (int gi = 0; gi < 6 && !found; gi++) {
                const int b2 = Gb[gi], r2 = r4[b2];
                const int nv_o = ((8 - r2) == o ? r2 : 0) + (r2 == o ? (8 - r2) : 0);
                const int cnt = 2 * nv_o;
                if (cnt > 0 && jj < cnt) {
                    b = b2; h = Gh[gi]; Lsel = o;
                    half = jj / nv_o;
                    int pos = jj % nv_o;
                    int S = (((8 - r2) == o) ? rmask[b2] : 0)
                          | ((r2 == o) ? ((~rmask[b2]) & 0xff) : 0);
                    for (int vv = 0; vv < 8; vv++)
                        if ((S >> vv) & 1) { if (pos == 0) { v = vv; break; } pos--; }
                    found = true;
                } else jj -= cnt;
            }
        }
    }
    // ------------------------------------------------------

    const int t = threadIdx.x, wave = t >> 6, lane = t & 63;
    const int m = lane & 15, quad = lane >> 4;
    const int n0 = half * 128 + wave * 32;

    __shared__ unsigned short Ks[128][64];   // [key][dim], dg' = dg ^ (key&7)
    __shared__ unsigned short Vs[64][128];   // [dim][key], kg' = kg ^ (dim&15)

    const int my_ref = (rmask[b] >> v) & 1;
    const unsigned amask = my_ref ? (unsigned)((~rmask[b]) & 0xff)
                                  : (unsigned)rmask[b];
    const int nChunks = 2 * Lsel;

    const float c1 = 0.18033688f;  // 0.125 * log2(e)

    // Q B-frags: B[n=query=m][k=quad*8+j], two 32-dim K-steps
    short8 aq[2][2];
    #pragma unroll
    for (int qt = 0; qt < 2; qt++) {
        const size_t row = (size_t)((b * VDIM + v) * NDIM) + n0 + qt * 16 + m;
        #pragma unroll
        for (int ks = 0; ks < 2; ks++)
            aq[qt][ks] = *(const short8*)&qkv[row * C3 + h * DHE + ks * 32 + quad * 8];
    }

    float rs[2] = {0.f, 0.f};     // per-lane l partial, query = qt*16 + m
    float4v O[2][4] = {};

    // staging thread coords
    const int k_key = t >> 3, k_dg = t & 7;    // key = i*32 + k_key
    const int v_dim = t >> 4, v_kg = t & 15;   // dim = i*16 + v_dim

    // shfl sources for P redistribution (lane = quad*16 + m)
    const int src0 = ((quad & 1) << 5) + m;    // lane (m, 2*(quad&1))
    const int src1 = src0 + 16;                // lane (m, 2*(quad&1)+1)
    const bool hiq = (quad >> 1) != 0;         // use nt = kk*2+1

    const unsigned short* vTb = vT + (size_t)(b * HDIM + h) * DHE * KEYS;

    uint4 kreg[4], vreg[4];
    unsigned rem2 = amask;
    int wcur = __builtin_ffs((int)rem2) - 1;

    if (nChunks > 0) {
        const unsigned short* kb =
            qkv + (size_t)((b * VDIM + wcur) * NDIM) * C3 + CDIM + h * DHE;
        #pragma unroll
        for (int i = 0; i < 4; i++)
            kreg[i] = *(const uint4*)&kb[(size_t)(i * 32 + k_key) * C3 + k_dg * 8];
        #pragma unroll
        for (int i = 0; i < 4; i++)
            vreg[i] = *(const uint4*)&vTb[(size_t)(i * 16 + v_dim) * KEYS
                                          + wcur * NDIM + v_kg * 8];
    }

    for (int ci = 0; ci < nChunks; ci++) {
        __syncthreads();   // prev chunk's LDS reads complete
        #pragma unroll
        for (int i = 0; i < 4; i++)
            *(uint4*)&Ks[i * 32 + k_key][(k_dg ^ (k_key & 7)) * 8] = kreg[i];
        #pragma unroll
        for (int i = 0; i < 4; i++)
            *(uint4*)&Vs[i * 16 + v_dim][(v_kg ^ v_dim) * 8] = vreg[i];

        if (ci + 1 < nChunks) {   // prefetch next chunk into regs
            int wn, m0n;
            if ((ci & 1) == 0) { wn = wcur; m0n = 128; }
            else {
                unsigned r2 = rem2 & (rem2 - 1);
                wn = __builtin_ffs((int)r2) - 1; m0n = 0;
            }
            const unsigned short* kb =
                qkv + (size_t)((b * VDIM + wn) * NDIM + m0n) * C3 + CDIM + h * DHE;
            #pragma unroll
            for (int i = 0; i < 4; i++)
                kreg[i] = *(const uint4*)&kb[(size_t)(i * 32 + k_key) * C3 + k_dg * 8];
            #pragma unroll
            for (int i = 0; i < 4; i++)
                vreg[i] = *(const uint4*)&vTb[(size_t)(i * 16 + v_dim) * KEYS
                                              + wn * NDIM + m0n + v_kg * 8];
        }
        __syncthreads();   // LDS tiles visible

        // two 64-key halves: S^T tiles -> pq regs, then PV via shfl pulls
        #pragma unroll
        for (int hk = 0; hk < 2; hk++) {
            uint2 pq[2][4];   // [qt][kt], fully unrolled indices (reg-resident)
            #pragma unroll
            for (int kt = 0; kt < 4; kt++) {
                const int nt = hk * 4 + kt;
                // A-frag = K (lane m = key within tile)
                const short8 bk0 = *(const short8*)&Ks[nt * 16 + m][(quad ^ (m & 7)) * 8];
                const short8 bk1 = *(const short8*)&Ks[nt * 16 + m][((4 + quad) ^ (m & 7)) * 8];
                #pragma unroll
                for (int qt = 0; qt < 2; qt++) {
                    float4v s = {};
                    s = __builtin_amdgcn_mfma_f32_16x16x32_bf16(bk0, aq[qt][0], s, 0, 0, 0);
                    s = __builtin_amdgcn_mfma_f32_16x16x32_bf16(bk1, aq[qt][1], s, 0, 0, 0);
                    // s[r]: key = nt*16 + quad*4 + r, query = qt*16 + m
                    const float p0 = __builtin_amdgcn_exp2f(s[0] * c1);
                    const float p1 = __builtin_amdgcn_exp2f(s[1] * c1);
                    const float p2 = __builtin_amdgcn_exp2f(s[2] * c1);
                    const float p3 = __builtin_amdgcn_exp2f(s[3] * c1);
                    rs[qt] += (p0 + p1) + (p2 + p3);
                    pq[qt][kt].x = pk2(p0, p1);
                    pq[qt][kt].y = pk2(p2, p3);
                }
            }
            #pragma unroll
            for (int kk = 0; kk < 2; kk++) {
                // build A-frags: keys kk*32+quad*8+{0..7} of query m
                uint4 u[2];
                #pragma unroll
                for (int qt = 0; qt < 2; qt++) {
                    const unsigned lox  = __shfl(pq[qt][kk * 2].x,     src0);
                    const unsigned loy  = __shfl(pq[qt][kk * 2].y,     src0);
                    const unsigned hix  = __shfl(pq[qt][kk * 2 + 1].x, src0);
                    const unsigned hiy  = __shfl(pq[qt][kk * 2 + 1].y, src0);
                    const unsigned lox1 = __shfl(pq[qt][kk * 2].x,     src1);
                    const unsigned loy1 = __shfl(pq[qt][kk * 2].y,     src1);
                    const unsigned hix1 = __shfl(pq[qt][kk * 2 + 1].x, src1);
                    const unsigned hiy1 = __shfl(pq[qt][kk * 2 + 1].y, src1);
                    u[qt].x = hiq ? hix  : lox;
                    u[qt].y = hiq ? hiy  : loy;
                    u[qt].z = hiq ? hix1 : lox1;
                    u[qt].w = hiq ? hiy1 : loy1;
                }
                const short8 ap0 = __builtin_bit_cast(short8, u[0]);
                const short8 ap1 = __builtin_bit_cast(short8, u[1]);
                #pragma unroll
                for (int ct = 0; ct < 4; ct++) {
                    const short8 bv = *(const short8*)&Vs[ct * 16 + m]
                        [((hk * 8 + kk * 4 + quad) ^ m) * 8];
                    O[0][ct] = __builtin_amdgcn_mfma_f32_16x16x32_bf16(ap0, bv, O[0][ct], 0, 0, 0);
                    O[1][ct] = __builtin_amdgcn_mfma_f32_16x16x32_bf16(ap1, bv, O[1][ct], 0, 0, 0);
                }
            }
        }
        if (ci & 1) { rem2 &= rem2 - 1; wcur = __builtin_ffs((int)rem2) - 1; }
    }

    // final: reduce l across the 4 quad-copies, broadcast to O rows, write
    #pragma unroll
    for (int qt = 0; qt < 2; qt++) {
        float x = rs[qt];
        x += __shfl_xor(x, 16, 64);
        x += __shfl_xor(x, 32, 64);
        const float inv = (x > 0.f) ? 1.f / x : 0.f;   // query = qt*16 + m
        float invq[4];
        #pragma unroll
        for (int r = 0; r < 4; r++)
            invq[r] = __shfl(inv, quad * 4 + r, 64);   // query = qt*16+quad*4+r
        const size_t rowg = (size_t)((b * VDIM + v) * NDIM) + n0 + qt * 16 + quad * 4;
        #pragma unroll
        for (int ct = 0; ct < 4; ct++)
            #pragma unroll
            for (int r = 0; r < 4; r++)
                ctx[(rowg + r) * CDIM + h * DHE + ct * 16 + m] = f2bf(O[qt][ct][r] * invq[r]);
    }
}

// ---------------------------------------------------------------------------
// Out-proj GEMM, global_load_lds staging + XCD-chunked swizzle (48/XCD =
// 8 row-panels x 6 col-blocks); fp32 out + passthrough.
// ---------------------------------------------------------------------------
__global__ __launch_bounds__(256) void gemm_out_mfma(
    const unsigned short* __restrict__ A,   // ctx_b [8192][768] bf16
    const unsigned short* __restrict__ W,   // w_out bf16 [768][768]
    const float* __restrict__ bias,
    const float* __restrict__ feats,
    const int* __restrict__ is_ref,
    float* __restrict__ out)                // [8192][768] fp32
{
    __shared__ __attribute__((aligned(16))) unsigned short As[128][32];
    __shared__ __attribute__((aligned(16))) unsigned short Ws[128][32];
    const int t = threadIdx.x;
    const int wave = t >> 6, lane = t & 63;
    const int m = lane & 15, quad = lane >> 4;
    const int wr = (wave >> 1) * 64, wc = (wave & 1) * 64;

    const int lin = blockIdx.y * gridDim.x + blockIdx.x;
    const int cpx = (gridDim.x * gridDim.y) >> 3;
    const int swz = (lin & 7) * cpx + (lin >> 3);
    const int row0 = (swz / gridDim.x) * 128, col0 = (swz % gridDim.x) * 128;

    const int sr = t >> 2, sk = (t & 3) * 8;
    const unsigned short* ag = &A[(size_t)(row0 + sr) * CDIM + sk];
    const unsigned short* wg = &W[(size_t)(col0 + sr) * CDIM + sk];
    unsigned short* la0 = &As[sr][sk];
    unsigned short* la1 = &As[64 + sr][sk];
    unsigned short* lw0 = &Ws[sr][sk];
    unsigned short* lw1 = &Ws[64 + sr][sk];

    float4v acc[4][4] = {};

    for (int k0 = 0; k0 < CDIM; k0 += 32) {
        gld_lds16(ag + k0, la0);
        gld_lds16(ag + (size_t)64 * CDIM + k0, la1);
        gld_lds16(wg + k0, lw0);
        gld_lds16(wg + (size_t)64 * CDIM + k0, lw1);
        __syncthreads();
        short8 a[4], b[4];
        #pragma unroll
        for (int rt = 0; rt < 4; rt++)
            a[rt] = *(const short8*)&As[wr + rt * 16 + m][quad * 8];
        #pragma unroll
        for (int ct = 0; ct < 4; ct++)
            b[ct] = *(const short8*)&Ws[wc + ct * 16 + m][quad * 8];
        #pragma unroll
        for (int rt = 0; rt < 4; rt++)
            #pragma unroll
            for (int ct = 0; ct < 4; ct++)
                acc[rt][ct] = __builtin_amdgcn_mfma_f32_16x16x32_bf16(
                    a[rt], b[ct], acc[rt][ct], 0, 0, 0);
        __syncthreads();
    }

    const int bidx = row0 / (VDIM * NDIM);
    const int vidx = (row0 / NDIM) % VDIM;
    const int my = is_ref[bidx * VDIM + vidx];
    bool has = false;
    #pragma unroll
    for (int w = 0; w < VDIM; w++) has = has || (is_ref[bidx * VDIM + w] != my);

    #pragma unroll
    for (int ct = 0; ct < 4; ct++) {
        const int col = col0 + wc + ct * 16 + m;
        const float bv = bias[col];
        #pragma unroll
        for (int rt = 0; rt < 4; rt++) {
            const size_t row = (size_t)row0 + wr + rt * 16 + quad * 4;
            #pragma unroll
            for (int r = 0; r < 4; r++) {
                float o = acc[rt][ct][r] + bv;
                if (!has) o = feats[(row + r) * CDIM + col];
                out[(row + r) * CDIM + col] = o;
            }
        }
    }
}

extern "C" void kernel_launch(void* const* d_in, const int* in_sizes, int n_in,
                              void* d_out, int out_size, void* d_ws, size_t ws_size,
                              hipStream_t stream) {
    const float* feats = (const float*)d_in[0];
    const int*   is_ref = (const int*)d_in[1];
    const float* w_qkv = (const float*)d_in[2];
    const float* b_qkv = (const float*)d_in[3];
    const float* w_out = (const float*)d_in[4];
    const float* b_out = (const float*)d_in[5];
    float* out = (float*)d_out;

    unsigned short* qkv_b = (unsigned short*)d_ws;                 // 8192x2304
    unsigned short* vT    = qkv_b + (size_t)ROWS * C3;             // 4x12x64x2048
    unsigned short* ctx_b = vT + (size_t)BDIM * HDIM * DHE * KEYS; // 8192x768
    unsigned short* A_bf  = ctx_b + (size_t)ROWS * CDIM;           // 8192x768
    unsigned short* Wq_bf = A_bf + (size_t)ROWS * CDIM;            // 2304x768
    unsigned short* Wo_bf = Wq_bf + (size_t)C3 * CDIM;             // 768x768

    cast_bf16_all<<<dim3((NA8 + NW8 + NO8) / 256), 256, 0, stream>>>(
        feats, w_qkv, w_out, A_bf, Wq_bf, Wo_bf);

    dim3 g1(C3 / 128, ROWS / 128);                                 // 18 x 64
    gemm_qkv_mfma<<<g1, 256, 0, stream>>>(A_bf, Wq_bf, b_qkv, qkv_b, vT);

    attn_mfma<<<dim3(768), 256, 0, stream>>>(qkv_b, vT, is_ref, ctx_b);

    dim3 g3(CDIM / 128, ROWS / 128);                               // 6 x 64
    gemm_out_mfma<<<g3, 256, 0, stream>>>(ctx_b, Wo_bf, b_out, feats, is_ref, out);
    (void)in_sizes; (void)n_in; (void)out_size; (void)ws_size;
}

// Round 10
// 237.283 us; speedup vs baseline: 1.3426x; 1.0289x over previous
//
#include <hip/hip_runtime.h>
#include <hip/hip_bf16.h>
#include <math.h>

#define BDIM 4
#define VDIM 8
#define NDIM 256
#define CDIM 768
#define HDIM 12
#define DHE  64
#define C3   (3*CDIM)
#define ROWS (BDIM*VDIM*NDIM)
#define KEYS (VDIM*NDIM)   // 2048

typedef __attribute__((ext_vector_type(8))) short short8;   // 8 bf16 = 4 VGPR
typedef __attribute__((ext_vector_type(4))) float float4v;  // MFMA acc

__device__ inline unsigned short f2bf(float f) {
    unsigned int u = __builtin_bit_cast(unsigned int, f);
    u += 0x7fffu + ((u >> 16) & 1u);   // RNE
    return (unsigned short)(u >> 16);
}

// packed f32x2 -> bf16x2 in a uint (low half = a, high half = b), RNE
__device__ __forceinline__ unsigned int pk2(float a, float b) {
    return (unsigned int)f2bf(a) | ((unsigned int)f2bf(b) << 16);
}

// 8 fp32 (two float4) -> uint4 of 8 bf16
__device__ __forceinline__ uint4 pk8(float4 a, float4 b) {
    uint4 r;
    r.x = pk2(a.x, a.y); r.y = pk2(a.z, a.w);
    r.z = pk2(b.x, b.y); r.w = pk2(b.z, b.w);
    return r;
}

// async 16B global -> LDS (wave-uniform base + lane*16; lane-order == LDS order)
__device__ __forceinline__ void gld_lds16(const unsigned short* g, unsigned short* l) {
    __builtin_amdgcn_global_load_lds(
        (const __attribute__((address_space(1))) void*)g,
        (__attribute__((address_space(3))) void*)l, 16, 0, 0);
}

// ---------------------------------------------------------------------------
// One-shot fp32 -> bf16 pre-cast of feats, w_qkv, w_out (memory-bound ~9us).
// ---------------------------------------------------------------------------
#define NA8 786432   // 8192*768/8
#define NW8 221184   // 2304*768/8
#define NO8 73728    //  768*768/8

__global__ __launch_bounds__(256) void cast_bf16_all(
    const float* __restrict__ fA, const float* __restrict__ fW,
    const float* __restrict__ fO,
    unsigned short* __restrict__ bA, unsigned short* __restrict__ bW,
    unsigned short* __restrict__ bO)
{
    const int gid = blockIdx.x * 256 + threadIdx.x;
    const float* src;
    unsigned short* dst;
    int idx;
    if (gid < NA8)            { src = fA; dst = bA; idx = gid; }
    else if (gid < NA8 + NW8) { src = fW; dst = bW; idx = gid - NA8; }
    else                      { src = fO; dst = bO; idx = gid - NA8 - NW8; }
    const float4* p = (const float4*)(src + (size_t)idx * 8);
    *(uint4*)(dst + (size_t)idx * 8) = pk8(p[0], p[1]);
}

// ---------------------------------------------------------------------------
// Fused QKV GEMM. R10: BK=64 via twin [128][32] LDS buffers — one barrier
// pair per 64 K (12 iters instead of 24). Per-pass body identical to the
// m97 step-3 structure (same frag regs, same LDS bank pattern); the vmcnt(0)
// +lgkmcnt(0) drain before each s_barrier (the documented ~20% structural
// stall) now amortizes over 2x the MFMA. XCD-chunked swizzle kept (R9: +4us).
// ---------------------------------------------------------------------------
__global__ __launch_bounds__(256) void gemm_qkv_mfma(
    const unsigned short* __restrict__ A,    // feats bf16 [8192][768]
    const unsigned short* __restrict__ W,    // w_qkv bf16 [2304][768]
    const float* __restrict__ bias,
    unsigned short* __restrict__ out,        // qkv [8192][2304] bf16 (Q,K only)
    unsigned short* __restrict__ vT)         // [4][12][64][2048] bf16
{
    __shared__ __attribute__((aligned(16))) unsigned short As[2][128][32];
    __shared__ __attribute__((aligned(16))) unsigned short Ws[2][128][32];
    const int t = threadIdx.x;
    const int wave = t >> 6, lane = t & 63;
    const int m = lane & 15, quad = lane >> 4;
    const int wr = (wave >> 1) * 64, wc = (wave & 1) * 64;

    const int lin = blockIdx.y * gridDim.x + blockIdx.x;
    const int cpx = (gridDim.x * gridDim.y) >> 3;
    const int swz = (lin & 7) * cpx + (lin >> 3);
    const int row0 = (swz / gridDim.x) * 128, col0 = (swz % gridDim.x) * 128;

    // staging: thread t owns row (t>>2), k-chunk (t&3)*8 -> LDS byte t*16
    const int sr = t >> 2, sk = (t & 3) * 8;
    const unsigned short* ag = &A[(size_t)(row0 + sr) * CDIM + sk];
    const unsigned short* wg = &W[(size_t)(col0 + sr) * CDIM + sk];

    float4v acc[4][4] = {};

    for (int k0 = 0; k0 < CDIM; k0 += 64) {
        #pragma unroll
        for (int ks = 0; ks < 2; ks++) {
            gld_lds16(ag + k0 + ks * 32, &As[ks][sr][sk]);
            gld_lds16(ag + (size_t)64 * CDIM + k0 + ks * 32, &As[ks][64 + sr][sk]);
            gld_lds16(wg + k0 + ks * 32, &Ws[ks][sr][sk]);
            gld_lds16(wg + (size_t)64 * CDIM + k0 + ks * 32, &Ws[ks][64 + sr][sk]);
        }
        __syncthreads();
        #pragma unroll
        for (int ks = 0; ks < 2; ks++) {
            short8 a[4], b[4];
            #pragma unroll
            for (int rt = 0; rt < 4; rt++)
                a[rt] = *(const short8*)&As[ks][wr + rt * 16 + m][quad * 8];
            #pragma unroll
            for (int ct = 0; ct < 4; ct++)
                b[ct] = *(const short8*)&Ws[ks][wc + ct * 16 + m][quad * 8];
            #pragma unroll
            for (int rt = 0; rt < 4; rt++)
                #pragma unroll
                for (int ct = 0; ct < 4; ct++)
                    acc[rt][ct] = __builtin_amdgcn_mfma_f32_16x16x32_bf16(
                        a[rt], b[ct], acc[rt][ct], 0, 0, 0);
        }
        __syncthreads();
    }

    if (col0 < 2 * CDIM) {
        // Q/K epilogue -> qkv
        #pragma unroll
        for (int ct = 0; ct < 4; ct++) {
            const int col = col0 + wc + ct * 16 + m;
            const float bv = bias[col];
            #pragma unroll
            for (int rt = 0; rt < 4; rt++) {
                const size_t row = (size_t)row0 + wr + rt * 16 + quad * 4;
                #pragma unroll
                for (int r = 0; r < 4; r++)
                    out[(row + r) * C3 + col] = f2bf(acc[rt][ct][r] + bv);
            }
        }
    } else {
        // V epilogue -> transposed vT (4 consecutive keys per lane -> 8B)
        #pragma unroll
        for (int ct = 0; ct < 4; ct++) {
            const int vcol = col0 + wc + ct * 16 + m - 2 * CDIM;
            const int h = vcol >> 6, d = vcol & 63;
            const float bv = bias[col0 + wc + ct * 16 + m];
            #pragma unroll
            for (int rt = 0; rt < 4; rt++) {
                const int row = row0 + wr + rt * 16 + quad * 4;
                const int bidx = row >> 11, key = row & 2047;
                ushort4 pkv;
                pkv.x = f2bf(acc[rt][ct][0] + bv);
                pkv.y = f2bf(acc[rt][ct][1] + bv);
                pkv.z = f2bf(acc[rt][ct][2] + bv);
                pkv.w = f2bf(acc[rt][ct][3] + bv);
                *(ushort4*)&vT[((size_t)(bidx * HDIM + h) * DHE + d) * KEYS + key] = pkv;
            }
        }
    }
}

// ---------------------------------------------------------------------------
// MFMA flash attention. R10 = R8 inner loop REVERTED (R9's shfl-P was -2.4us:
// __shfl compiles to ds_permute — still LDS hardware — and the select chains
// added VALU to the critical path; freed LDS bought nothing at grid=768).
// Scheduler = R8 XCD-local LPT (37MB FETCH, occ 26%, attn 85.7us) unchanged.
// ---------------------------------------------------------------------------
__global__ __launch_bounds__(256, 3) void attn_mfma(
    const unsigned short* __restrict__ qkv,  // [8192][2304] bf16 (Q,K)
    const unsigned short* __restrict__ vT,   // [4][12][64][2048] bf16
    const int* __restrict__ is_ref,
    unsigned short* __restrict__ ctx)        // [8192][768] bf16
{
    const int g = blockIdx.x;
    const int myx = g & 7, cuu = (g >> 3) & 31, round = g >> 8;
    const int j = round * 32 + ((round & 1) ? (31 - cuu) : cuu); // slot 0..95

    // ---- per-batch ref info ----
    int rmask[4], r4[4];
    #pragma unroll
    for (int bb = 0; bb < 4; bb++) {
        int mask = 0;
        #pragma unroll
        for (int w = 0; w < VDIM; w++)
            if (is_ref[bb * VDIM + w] != 0) mask |= 1 << w;
        rmask[bb] = mask; r4[bb] = __popc(mask);
    }
    // ---- 1. sort batches desc by weight r(8-r) ----
    int ord[4] = {0, 1, 2, 3};
    #pragma unroll
    for (int i = 0; i < 3; i++)
        #pragma unroll
        for (int k = 0; k < 3 - i; k++) {
            const int wa = r4[ord[k]] * (8 - r4[ord[k]]);
            const int wb = r4[ord[k + 1]] * (8 - r4[ord[k + 1]]);
            if (wb > wa) { int tmp = ord[k]; ord[k] = ord[k + 1]; ord[k + 1] = tmp; }
        }
    // ---- 2. snake-deal 48 grps to 8 XCDs; collect my 6 (Gb, Gh) ----
    int Gb[6], Gh[6], ng = 0;
    for (int p = 0; p < 48; p++) {
        const int row = p >> 3, col = p & 7;
        const int x = (row & 1) ? (7 - col) : col;
        if (x == myx) { Gb[ng] = ord[p / 12]; Gh[ng] = p % 12; ng++; }
    }
    // ---- 3. class walk: find j-th task of this XCD (LPT order) ----
    int b = 0, h = 0, half = 0, v = 0, Lsel = 0;
    {
        int jj = j;
        bool found = false;
        for (int o = 8; o >= 0 && !found; o--) {
            for (int gi = 0; gi < 6 && !found; gi++) {
                const int b2 = Gb[gi], r2 = r4[b2];
                const int nv_o = ((8 - r2) == o ? r2 : 0) + (r2 == o ? (8 - r2) : 0);
                const int cnt = 2 * nv_o;
                if (cnt > 0 && jj < cnt) {
                    b = b2; h = Gh[gi]; Lsel = o;
                    half = jj / nv_o;
                    int pos = jj % nv_o;
                    int S = (((8 - r2) == o) ? rmask[b2] : 0)
                          | ((r2 == o) ? ((~rmask[b2]) & 0xff) : 0);
                    for (int vv = 0; vv < 8; vv++)
                        if ((S >> vv) & 1) { if (pos == 0) { v = vv; break; } pos--; }
                    found = true;
                } else jj -= cnt;
            }
        }
    }
    // ------------------------------------------------------

    const int t = threadIdx.x, wave = t >> 6, lane = t & 63;
    const int m = lane & 15, quad = lane >> 4;
    const int n0 = half * 128 + wave * 32;

    __shared__ unsigned short Ks[128][64];   // [key][dim], dg' = dg ^ (key&7)
    __shared__ unsigned short Vs[64][128];   // [dim][key], kg' = kg ^ (dim&15)
    __shared__ unsigned short Ps[4][32][72]; // [wave][query][64-key half]

    const int my_ref = (rmask[b] >> v) & 1;
    const unsigned amask = my_ref ? (unsigned)((~rmask[b]) & 0xff)
                                  : (unsigned)rmask[b];
    const int nChunks = 2 * Lsel;

    const float c1 = 0.18033688f;  // 0.125 * log2(e)

    // Q B-frags: B[n=query=m][k=quad*8+j], two 32-dim K-steps
    short8 aq[2][2];
    #pragma unroll
    for (int qt = 0; qt < 2; qt++) {
        const size_t row = (size_t)((b * VDIM + v) * NDIM) + n0 + qt * 16 + m;
        #pragma unroll
        for (int ks = 0; ks < 2; ks++)
            aq[qt][ks] = *(const short8*)&qkv[row * C3 + h * DHE + ks * 32 + quad * 8];
    }

    float rs[2] = {0.f, 0.f};     // per-lane l partial, query = qt*16 + m
    float4v O[2][4] = {};

    // staging thread coords
    const int k_key = t >> 3, k_dg = t & 7;    // key = i*32 + k_key
    const int v_dim = t >> 4, v_kg = t & 15;   // dim = i*16 + v_dim

    const unsigned short* vTb = vT + (size_t)(b * HDIM + h) * DHE * KEYS;

    uint4 kreg[4], vreg[4];
    unsigned rem2 = amask;
    int wcur = __builtin_ffs((int)rem2) - 1;

    if (nChunks > 0) {
        const unsigned short* kb =
            qkv + (size_t)((b * VDIM + wcur) * NDIM) * C3 + CDIM + h * DHE;
        #pragma unroll
        for (int i = 0; i < 4; i++)
            kreg[i] = *(const uint4*)&kb[(size_t)(i * 32 + k_key) * C3 + k_dg * 8];
        #pragma unroll
        for (int i = 0; i < 4; i++)
            vreg[i] = *(const uint4*)&vTb[(size_t)(i * 16 + v_dim) * KEYS
                                          + wcur * NDIM + v_kg * 8];
    }

    for (int ci = 0; ci < nChunks; ci++) {
        __syncthreads();   // prev chunk's LDS reads complete
        #pragma unroll
        for (int i = 0; i < 4; i++)
            *(uint4*)&Ks[i * 32 + k_key][(k_dg ^ (k_key & 7)) * 8] = kreg[i];
        #pragma unroll
        for (int i = 0; i < 4; i++)
            *(uint4*)&Vs[i * 16 + v_dim][(v_kg ^ v_dim) * 8] = vreg[i];

        if (ci + 1 < nChunks) {   // prefetch next chunk into regs
            int wn, m0n;
            if ((ci & 1) == 0) { wn = wcur; m0n = 128; }
            else {
                unsigned r2 = rem2 & (rem2 - 1);
                wn = __builtin_ffs((int)r2) - 1; m0n = 0;
            }
            const unsigned short* kb =
                qkv + (size_t)((b * VDIM + wn) * NDIM + m0n) * C3 + CDIM + h * DHE;
            #pragma unroll
            for (int i = 0; i < 4; i++)
                kreg[i] = *(const uint4*)&kb[(size_t)(i * 32 + k_key) * C3 + k_dg * 8];
            #pragma unroll
            for (int i = 0; i < 4; i++)
                vreg[i] = *(const uint4*)&vTb[(size_t)(i * 16 + v_dim) * KEYS
                                              + wn * NDIM + m0n + v_kg * 8];
        }
        __syncthreads();   // LDS tiles visible

        // two 64-key halves: S^T tiles -> packed Ps, then PV for that half
        #pragma unroll
        for (int hk = 0; hk < 2; hk++) {
            #pragma unroll
            for (int kt = 0; kt < 4; kt++) {
                const int nt = hk * 4 + kt;
                // A-frag = K (lane m = key within tile)
                const short8 bk0 = *(const short8*)&Ks[nt * 16 + m][(quad ^ (m & 7)) * 8];
                const short8 bk1 = *(const short8*)&Ks[nt * 16 + m][((4 + quad) ^ (m & 7)) * 8];
                #pragma unroll
                for (int qt = 0; qt < 2; qt++) {
                    float4v s = {};
                    s = __builtin_amdgcn_mfma_f32_16x16x32_bf16(bk0, aq[qt][0], s, 0, 0, 0);
                    s = __builtin_amdgcn_mfma_f32_16x16x32_bf16(bk1, aq[qt][1], s, 0, 0, 0);
                    // s[r]: key = nt*16 + quad*4 + r, query = qt*16 + m
                    const float p0 = __builtin_amdgcn_exp2f(s[0] * c1);
                    const float p1 = __builtin_amdgcn_exp2f(s[1] * c1);
                    const float p2 = __builtin_amdgcn_exp2f(s[2] * c1);
                    const float p3 = __builtin_amdgcn_exp2f(s[3] * c1);
                    rs[qt] += (p0 + p1) + (p2 + p3);
                    uint2 pw;
                    pw.x = pk2(p0, p1);
                    pw.y = pk2(p2, p3);
                    *(uint2*)&Ps[wave][qt * 16 + m][kt * 16 + quad * 4] = pw;
                }
            }
            #pragma unroll
            for (int kk = 0; kk < 2; kk++) {
                const short8 ap0 = *(const short8*)&Ps[wave][m][kk * 32 + quad * 8];
                const short8 ap1 = *(const short8*)&Ps[wave][16 + m][kk * 32 + quad * 8];
                #pragma unroll
                for (int ct = 0; ct < 4; ct++) {
                    const short8 bv = *(const short8*)&Vs[ct * 16 + m]
                        [((hk * 8 + kk * 4 + quad) ^ m) * 8];
                    O[0][ct] = __builtin_amdgcn_mfma_f32_16x16x32_bf16(ap0, bv, O[0][ct], 0, 0, 0);
                    O[1][ct] = __builtin_amdgcn_mfma_f32_16x16x32_bf16(ap1, bv, O[1][ct], 0, 0, 0);
                }
            }
        }
        if (ci & 1) { rem2 &= rem2 - 1; wcur = __builtin_ffs((int)rem2) - 1; }
    }

    // final: reduce l across the 4 quad-copies, broadcast to O rows, write
    #pragma unroll
    for (int qt = 0; qt < 2; qt++) {
        float x = rs[qt];
        x += __shfl_xor(x, 16, 64);
        x += __shfl_xor(x, 32, 64);
        const float inv = (x > 0.f) ? 1.f / x : 0.f;   // query = qt*16 + m
        float invq[4];
        #pragma unroll
        for (int r = 0; r < 4; r++)
            invq[r] = __shfl(inv, quad * 4 + r, 64);   // query = qt*16+quad*4+r
        const size_t rowg = (size_t)((b * VDIM + v) * NDIM) + n0 + qt * 16 + quad * 4;
        #pragma unroll
        for (int ct = 0; ct < 4; ct++)
            #pragma unroll
            for (int r = 0; r < 4; r++)
                ctx[(rowg + r) * CDIM + h * DHE + ct * 16 + m] = f2bf(O[qt][ct][r] * invq[r]);
    }
}

// ---------------------------------------------------------------------------
// Out-proj GEMM. R10: same BK=64 twin-buffer change; XCD swizzle kept.
// fp32 out + passthrough.
// ---------------------------------------------------------------------------
__global__ __launch_bounds__(256) void gemm_out_mfma(
    const unsigned short* __restrict__ A,   // ctx_b [8192][768] bf16
    const unsigned short* __restrict__ W,   // w_out bf16 [768][768]
    const float* __restrict__ bias,
    const float* __restrict__ feats,
    const int* __restrict__ is_ref,
    float* __restrict__ out)                // [8192][768] fp32
{
    __shared__ __attribute__((aligned(16))) unsigned short As[2][128][32];
    __shared__ __attribute__((aligned(16))) unsigned short Ws[2][128][32];
    const int t = threadIdx.x;
    const int wave = t >> 6, lane = t & 63;
    const int m = lane & 15, quad = lane >> 4;
    const int wr = (wave >> 1) * 64, wc = (wave & 1) * 64;

    const int lin = blockIdx.y * gridDim.x + blockIdx.x;
    const int cpx = (gridDim.x * gridDim.y) >> 3;
    const int swz = (lin & 7) * cpx + (lin >> 3);
    const int row0 = (swz / gridDim.x) * 128, col0 = (swz % gridDim.x) * 128;

    const int sr = t >> 2, sk = (t & 3) * 8;
    const unsigned short* ag = &A[(size_t)(row0 + sr) * CDIM + sk];
    const unsigned short* wg = &W[(size_t)(col0 + sr) * CDIM + sk];

    float4v acc[4][4] = {};

    for (int k0 = 0; k0 < CDIM; k0 += 64) {
        #pragma unroll
        for (int ks = 0; ks < 2; ks++) {
            gld_lds16(ag + k0 + ks * 32, &As[ks][sr][sk]);
            gld_lds16(ag + (size_t)64 * CDIM + k0 + ks * 32, &As[ks][64 + sr][sk]);
            gld_lds16(wg + k0 + ks * 32, &Ws[ks][sr][sk]);
            gld_lds16(wg + (size_t)64 * CDIM + k0 + ks * 32, &Ws[ks][64 + sr][sk]);
        }
        __syncthreads();
        #pragma unroll
        for (int ks = 0; ks < 2; ks++) {
            short8 a[4], b[4];
            #pragma unroll
            for (int rt = 0; rt < 4; rt++)
                a[rt] = *(const short8*)&As[ks][wr + rt * 16 + m][quad * 8];
            #pragma unroll
            for (int ct = 0; ct < 4; ct++)
                b[ct] = *(const short8*)&Ws[ks][wc + ct * 16 + m][quad * 8];
            #pragma unroll
            for (int rt = 0; rt < 4; rt++)
                #pragma unroll
                for (int ct = 0; ct < 4; ct++)
                    acc[rt][ct] = __builtin_amdgcn_mfma_f32_16x16x32_bf16(
                        a[rt], b[ct], acc[rt][ct], 0, 0, 0);
        }
        __syncthreads();
    }

    const int bidx = row0 / (VDIM * NDIM);
    const int vidx = (row0 / NDIM) % VDIM;
    const int my = is_ref[bidx * VDIM + vidx];
    bool has = false;
    #pragma unroll
    for (int w = 0; w < VDIM; w++) has = has || (is_ref[bidx * VDIM + w] != my);

    #pragma unroll
    for (int ct = 0; ct < 4; ct++) {
        const int col = col0 + wc + ct * 16 + m;
        const float bv = bias[col];
        #pragma unroll
        for (int rt = 0; rt < 4; rt++) {
            const size_t row = (size_t)row0 + wr + rt * 16 + quad * 4;
            #pragma unroll
            for (int r = 0; r < 4; r++) {
                float o = acc[rt][ct][r] + bv;
                if (!has) o = feats[(row + r) * CDIM + col];
                out[(row + r) * CDIM + col] = o;
            }
        }
    }
}

extern "C" void kernel_launch(void* const* d_in, const int* in_sizes, int n_in,
                              void* d_out, int out_size, void* d_ws, size_t ws_size,
                              hipStream_t stream) {
    const float* feats = (const float*)d_in[0];
    const int*   is_ref = (const int*)d_in[1];
    const float* w_qkv = (const float*)d_in[2];
    const float* b_qkv = (const float*)d_in[3];
    const float* w_out = (const float*)d_in[4];
    const float* b_out = (const float*)d_in[5];
    float* out = (float*)d_out;

    unsigned short* qkv_b = (unsigned short*)d_ws;                 // 8192x2304
    unsigned short* vT    = qkv_b + (size_t)ROWS * C3;             // 4x12x64x2048
    unsigned short* ctx_b = vT + (size_t)BDIM * HDIM * DHE * KEYS; // 8192x768
    unsigned short* A_bf  = ctx_b + (size_t)ROWS * CDIM;           // 8192x768
    unsigned short* Wq_bf = A_bf + (size_t)ROWS * CDIM;            // 2304x768
    unsigned short* Wo_bf = Wq_bf + (size_t)C3 * CDIM;             // 768x768

    cast_bf16_all<<<dim3((NA8 + NW8 + NO8) / 256), 256, 0, stream>>>(
        feats, w_qkv, w_out, A_bf, Wq_bf, Wo_bf);

    dim3 g1(C3 / 128, ROWS / 128);                                 // 18 x 64
    gemm_qkv_mfma<<<g1, 256, 0, stream>>>(A_bf, Wq_bf, b_qkv, qkv_b, vT);

    attn_mfma<<<dim3(768), 256, 0, stream>>>(qkv_b, vT, is_ref, ctx_b);

    dim3 g3(CDIM / 128, ROWS / 128);                               // 6 x 64
    gemm_out_mfma<<<g3, 256, 0, stream>>>(ctx_b, Wo_bf, b_out, feats, is_ref, out);
    (void)in_sizes; (void)n_in; (void)out_size; (void)ws_size;
}

// Round 11
// 226.778 us; speedup vs baseline: 1.4048x; 1.0463x over previous
//
#include <hip/hip_runtime.h>
#include <hip/hip_bf16.h>
#include <math.h>

#define BDIM 4
#define VDIM 8
#define NDIM 256
#define CDIM 768
#define HDIM 12
#define DHE  64
#define C3   (3*CDIM)
#define ROWS (BDIM*VDIM*NDIM)
#define KEYS (VDIM*NDIM)   // 2048

typedef __attribute__((ext_vector_type(8))) short short8;   // 8 bf16 = 4 VGPR
typedef __attribute__((ext_vector_type(4))) float float4v;  // MFMA acc

__device__ inline unsigned short f2bf(float f) {
    unsigned int u = __builtin_bit_cast(unsigned int, f);
    u += 0x7fffu + ((u >> 16) & 1u);   // RNE
    return (unsigned short)(u >> 16);
}

// packed f32x2 -> bf16x2 in a uint (low half = a, high half = b), RNE
__device__ __forceinline__ unsigned int pk2(float a, float b) {
    return (unsigned int)f2bf(a) | ((unsigned int)f2bf(b) << 16);
}

// 8 fp32 (two float4) -> uint4 of 8 bf16
__device__ __forceinline__ uint4 pk8(float4 a, float4 b) {
    uint4 r;
    r.x = pk2(a.x, a.y); r.y = pk2(a.z, a.w);
    r.z = pk2(b.x, b.y); r.w = pk2(b.z, b.w);
    return r;
}

// async 16B global -> LDS (wave-uniform base + lane*16; lane-order == LDS order)
__device__ __forceinline__ void gld_lds16(const unsigned short* g, unsigned short* l) {
    __builtin_amdgcn_global_load_lds(
        (const __attribute__((address_space(1))) void*)g,
        (__attribute__((address_space(3))) void*)l, 16, 0, 0);
}

// ---------------------------------------------------------------------------
// One-shot fp32 -> bf16 pre-cast of feats, w_qkv, w_out (memory-bound ~9us).
// ---------------------------------------------------------------------------
#define NA8 786432   // 8192*768/8
#define NW8 221184   // 2304*768/8
#define NO8 73728    //  768*768/8

__global__ __launch_bounds__(256) void cast_bf16_all(
    const float* __restrict__ fA, const float* __restrict__ fW,
    const float* __restrict__ fO,
    unsigned short* __restrict__ bA, unsigned short* __restrict__ bW,
    unsigned short* __restrict__ bO)
{
    const int gid = blockIdx.x * 256 + threadIdx.x;
    const float* src;
    unsigned short* dst;
    int idx;
    if (gid < NA8)            { src = fA; dst = bA; idx = gid; }
    else if (gid < NA8 + NW8) { src = fW; dst = bW; idx = gid - NA8; }
    else                      { src = fO; dst = bO; idx = gid - NA8 - NW8; }
    const float4* p = (const float4*)(src + (size_t)idx * 8);
    *(uint4*)(dst + (size_t)idx * 8) = pk8(p[0], p[1]);
}

// ---------------------------------------------------------------------------
// Fused QKV GEMM. BK=64 twin-buffer (R10, -barriers) + XCD swizzle (R9).
// ---------------------------------------------------------------------------
__global__ __launch_bounds__(256) void gemm_qkv_mfma(
    const unsigned short* __restrict__ A,    // feats bf16 [8192][768]
    const unsigned short* __restrict__ W,    // w_qkv bf16 [2304][768]
    const float* __restrict__ bias,
    unsigned short* __restrict__ out,        // qkv [8192][2304] bf16 (Q,K only)
    unsigned short* __restrict__ vT)         // [4][12][64][2048] bf16
{
    __shared__ __attribute__((aligned(16))) unsigned short As[2][128][32];
    __shared__ __attribute__((aligned(16))) unsigned short Ws[2][128][32];
    const int t = threadIdx.x;
    const int wave = t >> 6, lane = t & 63;
    const int m = lane & 15, quad = lane >> 4;
    const int wr = (wave >> 1) * 64, wc = (wave & 1) * 64;

    const int lin = blockIdx.y * gridDim.x + blockIdx.x;
    const int cpx = (gridDim.x * gridDim.y) >> 3;
    const int swz = (lin & 7) * cpx + (lin >> 3);
    const int row0 = (swz / gridDim.x) * 128, col0 = (swz % gridDim.x) * 128;

    // staging: thread t owns row (t>>2), k-chunk (t&3)*8 -> LDS byte t*16
    const int sr = t >> 2, sk = (t & 3) * 8;
    const unsigned short* ag = &A[(size_t)(row0 + sr) * CDIM + sk];
    const unsigned short* wg = &W[(size_t)(col0 + sr) * CDIM + sk];

    float4v acc[4][4] = {};

    for (int k0 = 0; k0 < CDIM; k0 += 64) {
        #pragma unroll
        for (int ks = 0; ks < 2; ks++) {
            gld_lds16(ag + k0 + ks * 32, &As[ks][sr][sk]);
            gld_lds16(ag + (size_t)64 * CDIM + k0 + ks * 32, &As[ks][64 + sr][sk]);
            gld_lds16(wg + k0 + ks * 32, &Ws[ks][sr][sk]);
            gld_lds16(wg + (size_t)64 * CDIM + k0 + ks * 32, &Ws[ks][64 + sr][sk]);
        }
        __syncthreads();
        #pragma unroll
        for (int ks = 0; ks < 2; ks++) {
            short8 a[4], b[4];
            #pragma unroll
            for (int rt = 0; rt < 4; rt++)
                a[rt] = *(const short8*)&As[ks][wr + rt * 16 + m][quad * 8];
            #pragma unroll
            for (int ct = 0; ct < 4; ct++)
                b[ct] = *(const short8*)&Ws[ks][wc + ct * 16 + m][quad * 8];
            #pragma unroll
            for (int rt = 0; rt < 4; rt++)
                #pragma unroll
                for (int ct = 0; ct < 4; ct++)
                    acc[rt][ct] = __builtin_amdgcn_mfma_f32_16x16x32_bf16(
                        a[rt], b[ct], acc[rt][ct], 0, 0, 0);
        }
        __syncthreads();
    }

    if (col0 < 2 * CDIM) {
        // Q/K epilogue -> qkv
        #pragma unroll
        for (int ct = 0; ct < 4; ct++) {
            const int col = col0 + wc + ct * 16 + m;
            const float bv = bias[col];
            #pragma unroll
            for (int rt = 0; rt < 4; rt++) {
                const size_t row = (size_t)row0 + wr + rt * 16 + quad * 4;
                #pragma unroll
                for (int r = 0; r < 4; r++)
                    out[(row + r) * C3 + col] = f2bf(acc[rt][ct][r] + bv);
            }
        }
    } else {
        // V epilogue -> transposed vT (4 consecutive keys per lane -> 8B)
        #pragma unroll
        for (int ct = 0; ct < 4; ct++) {
            const int vcol = col0 + wc + ct * 16 + m - 2 * CDIM;
            const int h = vcol >> 6, d = vcol & 63;
            const float bv = bias[col0 + wc + ct * 16 + m];
            #pragma unroll
            for (int rt = 0; rt < 4; rt++) {
                const int row = row0 + wr + rt * 16 + quad * 4;
                const int bidx = row >> 11, key = row & 2047;
                ushort4 pkv;
                pkv.x = f2bf(acc[rt][ct][0] + bv);
                pkv.y = f2bf(acc[rt][ct][1] + bv);
                pkv.z = f2bf(acc[rt][ct][2] + bv);
                pkv.w = f2bf(acc[rt][ct][3] + bv);
                *(ushort4*)&vT[((size_t)(bidx * HDIM + h) * DHE + d) * KEYS + key] = pkv;
            }
        }
    }
}

// ---------------------------------------------------------------------------
// MFMA flash attention. R11: K/V DOUBLE-BUFFER at KVBLK=64.
// R10's loop paid a serialized write window per chunk: [bar] ds_write K/V
// + lgkm drain [bar] compute — staging could never overlap compute (same
// buffer). Now chunks are 64 keys, Ks[2]/Vs[2] ping-pong (LDS still 50KB ->
// 3 blocks/CU), ONE barrier per chunk: write chunk c+1 into buf^1 and issue
// global loads for c+2 WHILE computing chunk c from buf. Same barrier count
// per key, write window hidden, ~1 chunk of HBM lead time.
// View walk via packed-nibble vpack (no runtime-indexed array -> no scratch).
// Scheduler = R8 XCD-local LPT, QK/PV math, Ps, epilogue: unchanged.
// ---------------------------------------------------------------------------
__global__ __launch_bounds__(256, 3) void attn_mfma(
    const unsigned short* __restrict__ qkv,  // [8192][2304] bf16 (Q,K)
    const unsigned short* __restrict__ vT,   // [4][12][64][2048] bf16
    const int* __restrict__ is_ref,
    unsigned short* __restrict__ ctx)        // [8192][768] bf16
{
    const int g = blockIdx.x;
    const int myx = g & 7, cuu = (g >> 3) & 31, round = g >> 8;
    const int j = round * 32 + ((round & 1) ? (31 - cuu) : cuu); // slot 0..95

    // ---- per-batch ref info ----
    int rmask[4], r4[4];
    #pragma unroll
    for (int bb = 0; bb < 4; bb++) {
        int mask = 0;
        #pragma unroll
        for (int w = 0; w < VDIM; w++)
            if (is_ref[bb * VDIM + w] != 0) mask |= 1 << w;
        rmask[bb] = mask; r4[bb] = __popc(mask);
    }
    // ---- 1. sort batches desc by weight r(8-r) ----
    int ord[4] = {0, 1, 2, 3};
    #pragma unroll
    for (int i = 0; i < 3; i++)
        #pragma unroll
        for (int k = 0; k < 3 - i; k++) {
            const int wa = r4[ord[k]] * (8 - r4[ord[k]]);
            const int wb = r4[ord[k + 1]] * (8 - r4[ord[k + 1]]);
            if (wb > wa) { int tmp = ord[k]; ord[k] = ord[k + 1]; ord[k + 1] = tmp; }
        }
    // ---- 2. snake-deal 48 grps to 8 XCDs; collect my 6 (Gb, Gh) ----
    int Gb[6], Gh[6], ng = 0;
    for (int p = 0; p < 48; p++) {
        const int row = p >> 3, col = p & 7;
        const int x = (row & 1) ? (7 - col) : col;
        if (x == myx) { Gb[ng] = ord[p / 12]; Gh[ng] = p % 12; ng++; }
    }
    // ---- 3. class walk: find j-th task of this XCD (LPT order) ----
    int b = 0, h = 0, half = 0, v = 0, Lsel = 0;
    {
        int jj = j;
        bool found = false;
        for (int o = 8; o >= 0 && !found; o--) {
            for (int gi = 0; gi < 6 && !found; gi++) {
                const int b2 = Gb[gi], r2 = r4[b2];
                const int nv_o = ((8 - r2) == o ? r2 : 0) + (r2 == o ? (8 - r2) : 0);
                const int cnt = 2 * nv_o;
                if (cnt > 0 && jj < cnt) {
                    b = b2; h = Gh[gi]; Lsel = o;
                    half = jj / nv_o;
                    int pos = jj % nv_o;
                    int S = (((8 - r2) == o) ? rmask[b2] : 0)
                          | ((r2 == o) ? ((~rmask[b2]) & 0xff) : 0);
                    for (int vv = 0; vv < 8; vv++)
                        if ((S >> vv) & 1) { if (pos == 0) { v = vv; break; } pos--; }
                    found = true;
                } else jj -= cnt;
            }
        }
    }
    // ------------------------------------------------------

    const int t = threadIdx.x, wave = t >> 6, lane = t & 63;
    const int m = lane & 15, quad = lane >> 4;
    const int n0 = half * 128 + wave * 32;

    __shared__ unsigned short Ks[2][64][64]; // [buf][key][dim], dg' = dg^(key&7)
    __shared__ unsigned short Vs[2][64][64]; // [buf][dim][key], kg' = kg^(dim&7)
    __shared__ unsigned short Ps[4][32][72]; // [wave][query][64-key chunk]

    const int my_ref = (rmask[b] >> v) & 1;
    const unsigned amask = my_ref ? (unsigned)((~rmask[b]) & 0xff)
                                  : (unsigned)rmask[b];
    const int nC = 4 * Lsel;                 // 64-key chunks

    // packed view list: nibble i = i-th set bit of amask
    unsigned vpack = 0;
    {
        unsigned rm = amask; int pi = 0;
        while (rm) { vpack |= (unsigned)(__builtin_ffs((int)rm) - 1) << (4 * pi);
                     rm &= rm - 1; pi++; }
    }

    const float c1 = 0.18033688f;  // 0.125 * log2(e)

    // Q B-frags: B[n=query=m][k=quad*8+j], two 32-dim K-steps
    short8 aq[2][2];
    #pragma unroll
    for (int qt = 0; qt < 2; qt++) {
        const size_t row = (size_t)((b * VDIM + v) * NDIM) + n0 + qt * 16 + m;
        #pragma unroll
        for (int ks = 0; ks < 2; ks++)
            aq[qt][ks] = *(const short8*)&qkv[row * C3 + h * DHE + ks * 32 + quad * 8];
    }

    float rs[2] = {0.f, 0.f};     // per-lane l partial, query = qt*16 + m
    float4v O[2][4] = {};

    // staging thread coords: 64 keys/dims, 4 threads each, 2x16B per thread
    const int s_row = t >> 2;                  // key (K) or dim (V), 0..63
    const int s_g   = (t & 3) * 2;             // first 8-short group, 0..7

    const unsigned short* vTb = vT + (size_t)(b * HDIM + h) * DHE * KEYS;
    const unsigned short* qkb = qkv + (size_t)(b * VDIM) * NDIM * C3 + CDIM + h * DHE;

    uint4 kreg[2], vreg[2];

    // chunk c -> view vpack nibble (c>>2), keybase (c&3)*64 within view
    #define LOADC(c)                                                           \
        {                                                                      \
            const int w_ = (int)((vpack >> (((c) >> 2) * 4)) & 15);            \
            const int kb_ = ((c) & 3) * 64;                                    \
            const unsigned short* kp = qkb + (size_t)(w_ * NDIM + kb_ + s_row) * C3; \
            kreg[0] = *(const uint4*)&kp[(s_g + 0) * 8];                       \
            kreg[1] = *(const uint4*)&kp[(s_g + 1) * 8];                       \
            const unsigned short* vp = vTb + (size_t)s_row * KEYS + w_ * NDIM + kb_; \
            vreg[0] = *(const uint4*)&vp[(s_g + 0) * 8];                       \
            vreg[1] = *(const uint4*)&vp[(s_g + 1) * 8];                       \
        }
    #define WRITEC(buf)                                                        \
        {                                                                      \
            *(uint4*)&Ks[buf][s_row][((s_g + 0) ^ (s_row & 7)) * 8] = kreg[0]; \
            *(uint4*)&Ks[buf][s_row][((s_g + 1) ^ (s_row & 7)) * 8] = kreg[1]; \
            *(uint4*)&Vs[buf][s_row][((s_g + 0) ^ (s_row & 7)) * 8] = vreg[0]; \
            *(uint4*)&Vs[buf][s_row][((s_g + 1) ^ (s_row & 7)) * 8] = vreg[1]; \
        }

    if (nC > 0) {
        LOADC(0);
        WRITEC(0);                 // no prior readers; pre-barrier write ok
        if (nC > 1) LOADC(1);
    }

    for (int c = 0; c < nC; c++) {
        const int buf = c & 1;
        __syncthreads();           // chunk c writes visible; buf^1 reads done
        if (c + 1 < nC) {
            WRITEC(buf ^ 1);       // stage chunk c+1 into other buffer
            if (c + 2 < nC) LOADC(c + 2);
        }

        // ---- compute chunk c (64 keys) from buf ----
        #pragma unroll
        for (int kt = 0; kt < 4; kt++) {
            const short8 bk0 = *(const short8*)&Ks[buf][kt * 16 + m][(quad ^ (m & 7)) * 8];
            const short8 bk1 = *(const short8*)&Ks[buf][kt * 16 + m][((4 + quad) ^ (m & 7)) * 8];
            #pragma unroll
            for (int qt = 0; qt < 2; qt++) {
                float4v s = {};
                s = __builtin_amdgcn_mfma_f32_16x16x32_bf16(bk0, aq[qt][0], s, 0, 0, 0);
                s = __builtin_amdgcn_mfma_f32_16x16x32_bf16(bk1, aq[qt][1], s, 0, 0, 0);
                // s[r]: key = kt*16 + quad*4 + r, query = qt*16 + m
                const float p0 = __builtin_amdgcn_exp2f(s[0] * c1);
                const float p1 = __builtin_amdgcn_exp2f(s[1] * c1);
                const float p2 = __builtin_amdgcn_exp2f(s[2] * c1);
                const float p3 = __builtin_amdgcn_exp2f(s[3] * c1);
                rs[qt] += (p0 + p1) + (p2 + p3);
                uint2 pw;
                pw.x = pk2(p0, p1);
                pw.y = pk2(p2, p3);
                *(uint2*)&Ps[wave][qt * 16 + m][kt * 16 + quad * 4] = pw;
            }
        }
        #pragma unroll
        for (int kk = 0; kk < 2; kk++) {
            const short8 ap0 = *(const short8*)&Ps[wave][m][kk * 32 + quad * 8];
            const short8 ap1 = *(const short8*)&Ps[wave][16 + m][kk * 32 + quad * 8];
            #pragma unroll
            for (int ct = 0; ct < 4; ct++) {
                const short8 bv = *(const short8*)&Vs[buf][ct * 16 + m]
                    [((kk * 4 + quad) ^ (m & 7)) * 8];
                O[0][ct] = __builtin_amdgcn_mfma_f32_16x16x32_bf16(ap0, bv, O[0][ct], 0, 0, 0);
                O[1][ct] = __builtin_amdgcn_mfma_f32_16x16x32_bf16(ap1, bv, O[1][ct], 0, 0, 0);
            }
        }
    }
    #undef LOADC
    #undef WRITEC

    // final: reduce l across the 4 quad-copies, broadcast to O rows, write
    #pragma unroll
    for (int qt = 0; qt < 2; qt++) {
        float x = rs[qt];
        x += __shfl_xor(x, 16, 64);
        x += __shfl_xor(x, 32, 64);
        const float inv = (x > 0.f) ? 1.f / x : 0.f;   // query = qt*16 + m
        float invq[4];
        #pragma unroll
        for (int r = 0; r < 4; r++)
            invq[r] = __shfl(inv, quad * 4 + r, 64);   // query = qt*16+quad*4+r
        const size_t rowg = (size_t)((b * VDIM + v) * NDIM) + n0 + qt * 16 + quad * 4;
        #pragma unroll
        for (int ct = 0; ct < 4; ct++)
            #pragma unroll
            for (int r = 0; r < 4; r++)
                ctx[(rowg + r) * CDIM + h * DHE + ct * 16 + m] = f2bf(O[qt][ct][r] * invq[r]);
    }
}

// ---------------------------------------------------------------------------
// Out-proj GEMM. BK=64 twin-buffer + XCD swizzle; fp32 out + passthrough.
// ---------------------------------------------------------------------------
__global__ __launch_bounds__(256) void gemm_out_mfma(
    const unsigned short* __restrict__ A,   // ctx_b [8192][768] bf16
    const unsigned short* __restrict__ W,   // w_out bf16 [768][768]
    const float* __restrict__ bias,
    const float* __restrict__ feats,
    const int* __restrict__ is_ref,
    float* __restrict__ out)                // [8192][768] fp32
{
    __shared__ __attribute__((aligned(16))) unsigned short As[2][128][32];
    __shared__ __attribute__((aligned(16))) unsigned short Ws[2][128][32];
    const int t = threadIdx.x;
    const int wave = t >> 6, lane = t & 63;
    const int m = lane & 15, quad = lane >> 4;
    const int wr = (wave >> 1) * 64, wc = (wave & 1) * 64;

    const int lin = blockIdx.y * gridDim.x + blockIdx.x;
    const int cpx = (gridDim.x * gridDim.y) >> 3;
    const int swz = (lin & 7) * cpx + (lin >> 3);
    const int row0 = (swz / gridDim.x) * 128, col0 = (swz % gridDim.x) * 128;

    const int sr = t >> 2, sk = (t & 3) * 8;
    const unsigned short* ag = &A[(size_t)(row0 + sr) * CDIM + sk];
    const unsigned short* wg = &W[(size_t)(col0 + sr) * CDIM + sk];

    float4v acc[4][4] = {};

    for (int k0 = 0; k0 < CDIM; k0 += 64) {
        #pragma unroll
        for (int ks = 0; ks < 2; ks++) {
            gld_lds16(ag + k0 + ks * 32, &As[ks][sr][sk]);
            gld_lds16(ag + (size_t)64 * CDIM + k0 + ks * 32, &As[ks][64 + sr][sk]);
            gld_lds16(wg + k0 + ks * 32, &Ws[ks][sr][sk]);
            gld_lds16(wg + (size_t)64 * CDIM + k0 + ks * 32, &Ws[ks][64 + sr][sk]);
        }
        __syncthreads();
        #pragma unroll
        for (int ks = 0; ks < 2; ks++) {
            short8 a[4], b[4];
            #pragma unroll
            for (int rt = 0; rt < 4; rt++)
                a[rt] = *(const short8*)&As[ks][wr + rt * 16 + m][quad * 8];
            #pragma unroll
            for (int ct = 0; ct < 4; ct++)
                b[ct] = *(const short8*)&Ws[ks][wc + ct * 16 + m][quad * 8];
            #pragma unroll
            for (int rt = 0; rt < 4; rt++)
                #pragma unroll
                for (int ct = 0; ct < 4; ct++)
                    acc[rt][ct] = __builtin_amdgcn_mfma_f32_16x16x32_bf16(
                        a[rt], b[ct], acc[rt][ct], 0, 0, 0);
        }
        __syncthreads();
    }

    const int bidx = row0 / (VDIM * NDIM);
    const int vidx = (row0 / NDIM) % VDIM;
    const int my = is_ref[bidx * VDIM + vidx];
    bool has = false;
    #pragma unroll
    for (int w = 0; w < VDIM; w++) has = has || (is_ref[bidx * VDIM + w] != my);

    #pragma unroll
    for (int ct = 0; ct < 4; ct++) {
        const int col = col0 + wc + ct * 16 + m;
        const float bv = bias[col];
        #pragma unroll
        for (int rt = 0; rt < 4; rt++) {
            const size_t row = (size_t)row0 + wr + rt * 16 + quad * 4;
            #pragma unroll
            for (int r = 0; r < 4; r++) {
                float o = acc[rt][ct][r] + bv;
                if (!has) o = feats[(row + r) * CDIM + col];
                out[(row + r) * CDIM + col] = o;
            }
        }
    }
}

extern "C" void kernel_launch(void* const* d_in, const int* in_sizes, int n_in,
                              void* d_out, int out_size, void* d_ws, size_t ws_size,
                              hipStream_t stream) {
    const float* feats = (const float*)d_in[0];
    const int*   is_ref = (const int*)d_in[1];
    const float* w_qkv = (const float*)d_in[2];
    const float* b_qkv = (const float*)d_in[3];
    const float* w_out = (const float*)d_in[4];
    const float* b_out = (const float*)d_in[5];
    float* out = (float*)d_out;

    unsigned short* qkv_b = (unsigned short*)d_ws;                 // 8192x2304
    unsigned short* vT    = qkv_b + (size_t)ROWS * C3;             // 4x12x64x2048
    unsigned short* ctx_b = vT + (size_t)BDIM * HDIM * DHE * KEYS; // 8192x768
    unsigned short* A_bf  = ctx_b + (size_t)ROWS * CDIM;           // 8192x768
    unsigned short* Wq_bf = A_bf + (size_t)ROWS * CDIM;            // 2304x768
    unsigned short* Wo_bf = Wq_bf + (size_t)C3 * CDIM;             // 768x768

    cast_bf16_all<<<dim3((NA8 + NW8 + NO8) / 256), 256, 0, stream>>>(
        feats, w_qkv, w_out, A_bf, Wq_bf, Wo_bf);

    dim3 g1(C3 / 128, ROWS / 128);                                 // 18 x 64
    gemm_qkv_mfma<<<g1, 256, 0, stream>>>(A_bf, Wq_bf, b_qkv, qkv_b, vT);

    attn_mfma<<<dim3(768), 256, 0, stream>>>(qkv_b, vT, is_ref, ctx_b);

    dim3 g3(CDIM / 128, ROWS / 128);                               // 6 x 64
    gemm_out_mfma<<<g3, 256, 0, stream>>>(ctx_b, Wo_bf, b_out, feats, is_ref, out);
    (void)in_sizes; (void)n_in; (void)out_size; (void)ws_size;
}

// Round 12
// 222.250 us; speedup vs baseline: 1.4334x; 1.0204x over previous
//
#include <hip/hip_runtime.h>
#include <hip/hip_bf16.h>
#include <math.h>

#define BDIM 4
#define VDIM 8
#define NDIM 256
#define CDIM 768
#define HDIM 12
#define DHE  64
#define C3   (3*CDIM)
#define ROWS (BDIM*VDIM*NDIM)
#define KEYS (VDIM*NDIM)   // 2048

typedef __attribute__((ext_vector_type(8))) short short8;   // 8 bf16 = 4 VGPR
typedef __attribute__((ext_vector_type(4))) float float4v;  // MFMA acc

// packed f32x2 -> bf16x2 (RNE) in ONE instruction — gfx950 v_cvt_pk_bf16_f32.
// (T12 recipe: no builtin on gfx950; the old manual-RNE f2bf was 5 VALU/val.)
__device__ __forceinline__ unsigned int pk2(float a, float b) {
    unsigned int r;
    asm("v_cvt_pk_bf16_f32 %0, %1, %2" : "=v"(r) : "v"(a), "v"(b));
    return r;
}

// 8 fp32 (two float4) -> uint4 of 8 bf16
__device__ __forceinline__ uint4 pk8(float4 a, float4 b) {
    uint4 r;
    r.x = pk2(a.x, a.y); r.y = pk2(a.z, a.w);
    r.z = pk2(b.x, b.y); r.w = pk2(b.z, b.w);
    return r;
}

// async 16B global -> LDS (wave-uniform base + lane*16; lane-order == LDS order)
__device__ __forceinline__ void gld_lds16(const unsigned short* g, unsigned short* l) {
    __builtin_amdgcn_global_load_lds(
        (const __attribute__((address_space(1))) void*)g,
        (__attribute__((address_space(3))) void*)l, 16, 0, 0);
}

#define QSCALE 0.18033688f   // 0.125 * log2(e), folded into stored Q

// ---------------------------------------------------------------------------
// One-shot fp32 -> bf16 pre-cast of feats, w_qkv, w_out (memory-bound ~9us).
// ---------------------------------------------------------------------------
#define NA8 786432   // 8192*768/8
#define NW8 221184   // 2304*768/8
#define NO8 73728    //  768*768/8

__global__ __launch_bounds__(256) void cast_bf16_all(
    const float* __restrict__ fA, const float* __restrict__ fW,
    const float* __restrict__ fO,
    unsigned short* __restrict__ bA, unsigned short* __restrict__ bW,
    unsigned short* __restrict__ bO)
{
    const int gid = blockIdx.x * 256 + threadIdx.x;
    const float* src;
    unsigned short* dst;
    int idx;
    if (gid < NA8)            { src = fA; dst = bA; idx = gid; }
    else if (gid < NA8 + NW8) { src = fW; dst = bW; idx = gid - NA8; }
    else                      { src = fO; dst = bO; idx = gid - NA8 - NW8; }
    const float4* p = (const float4*)(src + (size_t)idx * 8);
    *(uint4*)(dst + (size_t)idx * 8) = pk8(p[0], p[1]);
}

// ---------------------------------------------------------------------------
// Fused QKV GEMM. BK=64 twin-buffer + XCD swizzle. R12: Q-cols scaled by
// QSCALE at store (block-uniform: 768=6x128 so each col-block is purely
// Q/K/V), epilogue packs via v_cvt_pk (f2bf x64 -> cvt x32 + d16-hi stores).
// ---------------------------------------------------------------------------
__global__ __launch_bounds__(256) void gemm_qkv_mfma(
    const unsigned short* __restrict__ A,    // feats bf16 [8192][768]
    const unsigned short* __restrict__ W,    // w_qkv bf16 [2304][768]
    const float* __restrict__ bias,
    unsigned short* __restrict__ out,        // qkv [8192][2304] bf16 (Q,K only)
    unsigned short* __restrict__ vT)         // [4][12][64][2048] bf16
{
    __shared__ __attribute__((aligned(16))) unsigned short As[2][128][32];
    __shared__ __attribute__((aligned(16))) unsigned short Ws[2][128][32];
    const int t = threadIdx.x;
    const int wave = t >> 6, lane = t & 63;
    const int m = lane & 15, quad = lane >> 4;
    const int wr = (wave >> 1) * 64, wc = (wave & 1) * 64;

    const int lin = blockIdx.y * gridDim.x + blockIdx.x;
    const int cpx = (gridDim.x * gridDim.y) >> 3;
    const int swz = (lin & 7) * cpx + (lin >> 3);
    const int row0 = (swz / gridDim.x) * 128, col0 = (swz % gridDim.x) * 128;

    // staging: thread t owns row (t>>2), k-chunk (t&3)*8 -> LDS byte t*16
    const int sr = t >> 2, sk = (t & 3) * 8;
    const unsigned short* ag = &A[(size_t)(row0 + sr) * CDIM + sk];
    const unsigned short* wg = &W[(size_t)(col0 + sr) * CDIM + sk];

    float4v acc[4][4] = {};

    for (int k0 = 0; k0 < CDIM; k0 += 64) {
        #pragma unroll
        for (int ks = 0; ks < 2; ks++) {
            gld_lds16(ag + k0 + ks * 32, &As[ks][sr][sk]);
            gld_lds16(ag + (size_t)64 * CDIM + k0 + ks * 32, &As[ks][64 + sr][sk]);
            gld_lds16(wg + k0 + ks * 32, &Ws[ks][sr][sk]);
            gld_lds16(wg + (size_t)64 * CDIM + k0 + ks * 32, &Ws[ks][64 + sr][sk]);
        }
        __syncthreads();
        #pragma unroll
        for (int ks = 0; ks < 2; ks++) {
            short8 a[4], b[4];
            #pragma unroll
            for (int rt = 0; rt < 4; rt++)
                a[rt] = *(const short8*)&As[ks][wr + rt * 16 + m][quad * 8];
            #pragma unroll
            for (int ct = 0; ct < 4; ct++)
                b[ct] = *(const short8*)&Ws[ks][wc + ct * 16 + m][quad * 8];
            #pragma unroll
            for (int rt = 0; rt < 4; rt++)
                #pragma unroll
                for (int ct = 0; ct < 4; ct++)
                    acc[rt][ct] = __builtin_amdgcn_mfma_f32_16x16x32_bf16(
                        a[rt], b[ct], acc[rt][ct], 0, 0, 0);
        }
        __syncthreads();
    }

    if (col0 < 2 * CDIM) {
        // Q/K epilogue -> qkv (Q blocks pre-scaled by QSCALE; attn does exp2(s))
        const float qs = (col0 < CDIM) ? QSCALE : 1.0f;
        #pragma unroll
        for (int ct = 0; ct < 4; ct++) {
            const int col = col0 + wc + ct * 16 + m;
            const float bv = bias[col];
            #pragma unroll
            for (int rt = 0; rt < 4; rt++) {
                const size_t row = (size_t)row0 + wr + rt * 16 + quad * 4;
                const unsigned u01 = pk2((acc[rt][ct][0] + bv) * qs,
                                         (acc[rt][ct][1] + bv) * qs);
                const unsigned u23 = pk2((acc[rt][ct][2] + bv) * qs,
                                         (acc[rt][ct][3] + bv) * qs);
                out[(row + 0) * C3 + col] = (unsigned short)u01;
                out[(row + 1) * C3 + col] = (unsigned short)(u01 >> 16);
                out[(row + 2) * C3 + col] = (unsigned short)u23;
                out[(row + 3) * C3 + col] = (unsigned short)(u23 >> 16);
            }
        }
    } else {
        // V epilogue -> transposed vT (4 consecutive keys per lane -> 8B)
        #pragma unroll
        for (int ct = 0; ct < 4; ct++) {
            const int vcol = col0 + wc + ct * 16 + m - 2 * CDIM;
            const int h = vcol >> 6, d = vcol & 63;
            const float bv = bias[col0 + wc + ct * 16 + m];
            #pragma unroll
            for (int rt = 0; rt < 4; rt++) {
                const int row = row0 + wr + rt * 16 + quad * 4;
                const int bidx = row >> 11, key = row & 2047;
                uint2 pv2;
                pv2.x = pk2(acc[rt][ct][0] + bv, acc[rt][ct][1] + bv);
                pv2.y = pk2(acc[rt][ct][2] + bv, acc[rt][ct][3] + bv);
                *(uint2*)&vT[((size_t)(bidx * HDIM + h) * DHE + d) * KEYS + key] = pv2;
            }
        }
    }
}

// ---------------------------------------------------------------------------
// MFMA flash attention. R12: softmax VALU cut — v_cvt_pk_bf16_f32 for P
// packing (was 24 VALU/tile of manual RNE, now 2 instrs) and exp2(s) direct
// (scale pre-folded into Q). Chunk VALU ~300 -> ~120 ops.
// R11 structure otherwise unchanged: KVBLK=64 K/V double-buffer, one barrier
// per chunk, R8 XCD-local LPT scheduler.
// ---------------------------------------------------------------------------
__global__ __launch_bounds__(256, 3) void attn_mfma(
    const unsigned short* __restrict__ qkv,  // [8192][2304] bf16 (Qs,K)
    const unsigned short* __restrict__ vT,   // [4][12][64][2048] bf16
    const int* __restrict__ is_ref,
    unsigned short* __restrict__ ctx)        // [8192][768] bf16
{
    const int g = blockIdx.x;
    const int myx = g & 7, cuu = (g >> 3) & 31, round = g >> 8;
    const int j = round * 32 + ((round & 1) ? (31 - cuu) : cuu); // slot 0..95

    // ---- per-batch ref info ----
    int rmask[4], r4[4];
    #pragma unroll
    for (int bb = 0; bb < 4; bb++) {
        int mask = 0;
        #pragma unroll
        for (int w = 0; w < VDIM; w++)
            if (is_ref[bb * VDIM + w] != 0) mask |= 1 << w;
        rmask[bb] = mask; r4[bb] = __popc(mask);
    }
    // ---- 1. sort batches desc by weight r(8-r) ----
    int ord[4] = {0, 1, 2, 3};
    #pragma unroll
    for (int i = 0; i < 3; i++)
        #pragma unroll
        for (int k = 0; k < 3 - i; k++) {
            const int wa = r4[ord[k]] * (8 - r4[ord[k]]);
            const int wb = r4[ord[k + 1]] * (8 - r4[ord[k + 1]]);
            if (wb > wa) { int tmp = ord[k]; ord[k] = ord[k + 1]; ord[k + 1] = tmp; }
        }
    // ---- 2. snake-deal 48 grps to 8 XCDs; collect my 6 (Gb, Gh) ----
    int Gb[6], Gh[6], ng = 0;
    for (int p = 0; p < 48; p++) {
        const int row = p >> 3, col = p & 7;
        const int x = (row & 1) ? (7 - col) : col;
        if (x == myx) { Gb[ng] = ord[p / 12]; Gh[ng] = p % 12; ng++; }
    }
    // ---- 3. class walk: find j-th task of this XCD (LPT order) ----
    int b = 0, h = 0, half = 0, v = 0, Lsel = 0;
    {
        int jj = j;
        bool found = false;
        for (int o = 8; o >= 0 && !found; o--) {
            for (int gi = 0; gi < 6 && !found; gi++) {
                const int b2 = Gb[gi], r2 = r4[b2];
                const int nv_o = ((8 - r2) == o ? r2 : 0) + (r2 == o ? (8 - r2) : 0);
                const int cnt = 2 * nv_o;
                if (cnt > 0 && jj < cnt) {
                    b = b2; h = Gh[gi]; Lsel = o;
                    half = jj / nv_o;
                    int pos = jj % nv_o;
                    int S = (((8 - r2) == o) ? rmask[b2] : 0)
                          | ((r2 == o) ? ((~rmask[b2]) & 0xff) : 0);
                    for (int vv = 0; vv < 8; vv++)
                        if ((S >> vv) & 1) { if (pos == 0) { v = vv; break; } pos--; }
                    found = true;
                } else jj -= cnt;
            }
        }
    }
    // ------------------------------------------------------

    const int t = threadIdx.x, wave = t >> 6, lane = t & 63;
    const int m = lane & 15, quad = lane >> 4;
    const int n0 = half * 128 + wave * 32;

    __shared__ unsigned short Ks[2][64][64]; // [buf][key][dim], dg' = dg^(key&7)
    __shared__ unsigned short Vs[2][64][64]; // [buf][dim][key], kg' = kg^(dim&7)
    __shared__ unsigned short Ps[4][32][72]; // [wave][query][64-key chunk]

    const int my_ref = (rmask[b] >> v) & 1;
    const unsigned amask = my_ref ? (unsigned)((~rmask[b]) & 0xff)
                                  : (unsigned)rmask[b];
    const int nC = 4 * Lsel;                 // 64-key chunks

    // packed view list: nibble i = i-th set bit of amask
    unsigned vpack = 0;
    {
        unsigned rm = amask; int pi = 0;
        while (rm) { vpack |= (unsigned)(__builtin_ffs((int)rm) - 1) << (4 * pi);
                     rm &= rm - 1; pi++; }
    }

    // Q B-frags: B[n=query=m][k=quad*8+j], two 32-dim K-steps (Q pre-scaled)
    short8 aq[2][2];
    #pragma unroll
    for (int qt = 0; qt < 2; qt++) {
        const size_t row = (size_t)((b * VDIM + v) * NDIM) + n0 + qt * 16 + m;
        #pragma unroll
        for (int ks = 0; ks < 2; ks++)
            aq[qt][ks] = *(const short8*)&qkv[row * C3 + h * DHE + ks * 32 + quad * 8];
    }

    float rs[2] = {0.f, 0.f};     // per-lane l partial, query = qt*16 + m
    float4v O[2][4] = {};

    // staging thread coords: 64 keys/dims, 4 threads each, 2x16B per thread
    const int s_row = t >> 2;                  // key (K) or dim (V), 0..63
    const int s_g   = (t & 3) * 2;             // first 8-short group, 0..7

    const unsigned short* vTb = vT + (size_t)(b * HDIM + h) * DHE * KEYS;
    const unsigned short* qkb = qkv + (size_t)(b * VDIM) * NDIM * C3 + CDIM + h * DHE;

    uint4 kreg[2], vreg[2];

    // chunk c -> view vpack nibble (c>>2), keybase (c&3)*64 within view
    #define LOADC(c)                                                           \
        {                                                                      \
            const int w_ = (int)((vpack >> (((c) >> 2) * 4)) & 15);            \
            const int kb_ = ((c) & 3) * 64;                                    \
            const unsigned short* kp = qkb + (size_t)(w_ * NDIM + kb_ + s_row) * C3; \
            kreg[0] = *(const uint4*)&kp[(s_g + 0) * 8];                       \
            kreg[1] = *(const uint4*)&kp[(s_g + 1) * 8];                       \
            const unsigned short* vp = vTb + (size_t)s_row * KEYS + w_ * NDIM + kb_; \
            vreg[0] = *(const uint4*)&vp[(s_g + 0) * 8];                       \
            vreg[1] = *(const uint4*)&vp[(s_g + 1) * 8];                       \
        }
    #define WRITEC(buf)                                                        \
        {                                                                      \
            *(uint4*)&Ks[buf][s_row][((s_g + 0) ^ (s_row & 7)) * 8] = kreg[0]; \
            *(uint4*)&Ks[buf][s_row][((s_g + 1) ^ (s_row & 7)) * 8] = kreg[1]; \
            *(uint4*)&Vs[buf][s_row][((s_g + 0) ^ (s_row & 7)) * 8] = vreg[0]; \
            *(uint4*)&Vs[buf][s_row][((s_g + 1) ^ (s_row & 7)) * 8] = vreg[1]; \
        }

    if (nC > 0) {
        LOADC(0);
        WRITEC(0);                 // no prior readers; pre-barrier write ok
        if (nC > 1) LOADC(1);
    }

    for (int c = 0; c < nC; c++) {
        const int buf = c & 1;
        __syncthreads();           // chunk c writes visible; buf^1 reads done
        if (c + 1 < nC) {
            WRITEC(buf ^ 1);       // stage chunk c+1 into other buffer
            if (c + 2 < nC) LOADC(c + 2);
        }

        // ---- compute chunk c (64 keys) from buf ----
        #pragma unroll
        for (int kt = 0; kt < 4; kt++) {
            const short8 bk0 = *(const short8*)&Ks[buf][kt * 16 + m][(quad ^ (m & 7)) * 8];
            const short8 bk1 = *(const short8*)&Ks[buf][kt * 16 + m][((4 + quad) ^ (m & 7)) * 8];
            #pragma unroll
            for (int qt = 0; qt < 2; qt++) {
                float4v s = {};
                s = __builtin_amdgcn_mfma_f32_16x16x32_bf16(bk0, aq[qt][0], s, 0, 0, 0);
                s = __builtin_amdgcn_mfma_f32_16x16x32_bf16(bk1, aq[qt][1], s, 0, 0, 0);
                // s[r]: key = kt*16 + quad*4 + r, query = qt*16 + m
                const float p0 = __builtin_amdgcn_exp2f(s[0]);
                const float p1 = __builtin_amdgcn_exp2f(s[1]);
                const float p2 = __builtin_amdgcn_exp2f(s[2]);
                const float p3 = __builtin_amdgcn_exp2f(s[3]);
                rs[qt] += (p0 + p1) + (p2 + p3);
                uint2 pw;
                pw.x = pk2(p0, p1);
                pw.y = pk2(p2, p3);
                *(uint2*)&Ps[wave][qt * 16 + m][kt * 16 + quad * 4] = pw;
            }
        }
        #pragma unroll
        for (int kk = 0; kk < 2; kk++) {
            const short8 ap0 = *(const short8*)&Ps[wave][m][kk * 32 + quad * 8];
            const short8 ap1 = *(const short8*)&Ps[wave][16 + m][kk * 32 + quad * 8];
            #pragma unroll
            for (int ct = 0; ct < 4; ct++) {
                const short8 bv = *(const short8*)&Vs[buf][ct * 16 + m]
                    [((kk * 4 + quad) ^ (m & 7)) * 8];
                O[0][ct] = __builtin_amdgcn_mfma_f32_16x16x32_bf16(ap0, bv, O[0][ct], 0, 0, 0);
                O[1][ct] = __builtin_amdgcn_mfma_f32_16x16x32_bf16(ap1, bv, O[1][ct], 0, 0, 0);
            }
        }
    }
    #undef LOADC
    #undef WRITEC

    // final: reduce l across the 4 quad-copies, broadcast to O rows, write
    #pragma unroll
    for (int qt = 0; qt < 2; qt++) {
        float x = rs[qt];
        x += __shfl_xor(x, 16, 64);
        x += __shfl_xor(x, 32, 64);
        const float inv = (x > 0.f) ? 1.f / x : 0.f;   // query = qt*16 + m
        float invq[4];
        #pragma unroll
        for (int r = 0; r < 4; r++)
            invq[r] = __shfl(inv, quad * 4 + r, 64);   // query = qt*16+quad*4+r
        const size_t rowg = (size_t)((b * VDIM + v) * NDIM) + n0 + qt * 16 + quad * 4;
        #pragma unroll
        for (int ct = 0; ct < 4; ct++) {
            const int cc = h * DHE + ct * 16 + m;
            const unsigned u01 = pk2(O[qt][ct][0] * invq[0], O[qt][ct][1] * invq[1]);
            const unsigned u23 = pk2(O[qt][ct][2] * invq[2], O[qt][ct][3] * invq[3]);
            ctx[(rowg + 0) * CDIM + cc] = (unsigned short)u01;
            ctx[(rowg + 1) * CDIM + cc] = (unsigned short)(u01 >> 16);
            ctx[(rowg + 2) * CDIM + cc] = (unsigned short)u23;
            ctx[(rowg + 3) * CDIM + cc] = (unsigned short)(u23 >> 16);
        }
    }
}

// ---------------------------------------------------------------------------
// Out-proj GEMM. BK=64 twin-buffer + XCD swizzle; fp32 out + passthrough.
// ---------------------------------------------------------------------------
__global__ __launch_bounds__(256) void gemm_out_mfma(
    const unsigned short* __restrict__ A,   // ctx_b [8192][768] bf16
    const unsigned short* __restrict__ W,   // w_out bf16 [768][768]
    const float* __restrict__ bias,
    const float* __restrict__ feats,
    const int* __restrict__ is_ref,
    float* __restrict__ out)                // [8192][768] fp32
{
    __shared__ __attribute__((aligned(16))) unsigned short As[2][128][32];
    __shared__ __attribute__((aligned(16))) unsigned short Ws[2][128][32];
    const int t = threadIdx.x;
    const int wave = t >> 6, lane = t & 63;
    const int m = lane & 15, quad = lane >> 4;
    const int wr = (wave >> 1) * 64, wc = (wave & 1) * 64;

    const int lin = blockIdx.y * gridDim.x + blockIdx.x;
    const int cpx = (gridDim.x * gridDim.y) >> 3;
    const int swz = (lin & 7) * cpx + (lin >> 3);
    const int row0 = (swz / gridDim.x) * 128, col0 = (swz % gridDim.x) * 128;

    const int sr = t >> 2, sk = (t & 3) * 8;
    const unsigned short* ag = &A[(size_t)(row0 + sr) * CDIM + sk];
    const unsigned short* wg = &W[(size_t)(col0 + sr) * CDIM + sk];

    float4v acc[4][4] = {};

    for (int k0 = 0; k0 < CDIM; k0 += 64) {
        #pragma unroll
        for (int ks = 0; ks < 2; ks++) {
            gld_lds16(ag + k0 + ks * 32, &As[ks][sr][sk]);
            gld_lds16(ag + (size_t)64 * CDIM + k0 + ks * 32, &As[ks][64 + sr][sk]);
            gld_lds16(wg + k0 + ks * 32, &Ws[ks][sr][sk]);
            gld_lds16(wg + (size_t)64 * CDIM + k0 + ks * 32, &Ws[ks][64 + sr][sk]);
        }
        __syncthreads();
        #pragma unroll
        for (int ks = 0; ks < 2; ks++) {
            short8 a[4], b[4];
            #pragma unroll
            for (int rt = 0; rt < 4; rt++)
                a[rt] = *(const short8*)&As[ks][wr + rt * 16 + m][quad * 8];
            #pragma unroll
            for (int ct = 0; ct < 4; ct++)
                b[ct] = *(const short8*)&Ws[ks][wc + ct * 16 + m][quad * 8];
            #pragma unroll
            for (int rt = 0; rt < 4; rt++)
                #pragma unroll
                for (int ct = 0; ct < 4; ct++)
                    acc[rt][ct] = __builtin_amdgcn_mfma_f32_16x16x32_bf16(
                        a[rt], b[ct], acc[rt][ct], 0, 0, 0);
        }
        __syncthreads();
    }

    const int bidx = row0 / (VDIM * NDIM);
    const int vidx = (row0 / NDIM) % VDIM;
    const int my = is_ref[bidx * VDIM + vidx];
    bool has = false;
    #pragma unroll
    for (int w = 0; w < VDIM; w++) has = has || (is_ref[bidx * VDIM + w] != my);

    #pragma unroll
    for (int ct = 0; ct < 4; ct++) {
        const int col = col0 + wc + ct * 16 + m;
        const float bv = bias[col];
        #pragma unroll
        for (int rt = 0; rt < 4; rt++) {
            const size_t row = (size_t)row0 + wr + rt * 16 + quad * 4;
            #pragma unroll
            for (int r = 0; r < 4; r++) {
                float o = acc[rt][ct][r] + bv;
                if (!has) o = feats[(row + r) * CDIM + col];
                out[(row + r) * CDIM + col] = o;
            }
        }
    }
}

extern "C" void kernel_launch(void* const* d_in, const int* in_sizes, int n_in,
                              void* d_out, int out_size, void* d_ws, size_t ws_size,
                              hipStream_t stream) {
    const float* feats = (const float*)d_in[0];
    const int*   is_ref = (const int*)d_in[1];
    const float* w_qkv = (const float*)d_in[2];
    const float* b_qkv = (const float*)d_in[3];
    const float* w_out = (const float*)d_in[4];
    const float* b_out = (const float*)d_in[5];
    float* out = (float*)d_out;

    unsigned short* qkv_b = (unsigned short*)d_ws;                 // 8192x2304
    unsigned short* vT    = qkv_b + (size_t)ROWS * C3;             // 4x12x64x2048
    unsigned short* ctx_b = vT + (size_t)BDIM * HDIM * DHE * KEYS; // 8192x768
    unsigned short* A_bf  = ctx_b + (size_t)ROWS * CDIM;           // 8192x768
    unsigned short* Wq_bf = A_bf + (size_t)ROWS * CDIM;            // 2304x768
    unsigned short* Wo_bf = Wq_bf + (size_t)C3 * CDIM;             // 768x768

    cast_bf16_all<<<dim3((NA8 + NW8 + NO8) / 256), 256, 0, stream>>>(
        feats, w_qkv, w_out, A_bf, Wq_bf, Wo_bf);

    dim3 g1(C3 / 128, ROWS / 128);                                 // 18 x 64
    gemm_qkv_mfma<<<g1, 256, 0, stream>>>(A_bf, Wq_bf, b_qkv, qkv_b, vT);

    attn_mfma<<<dim3(768), 256, 0, stream>>>(qkv_b, vT, is_ref, ctx_b);

    dim3 g3(CDIM / 128, ROWS / 128);                               // 6 x 64
    gemm_out_mfma<<<g3, 256, 0, stream>>>(ctx_b, Wo_bf, b_out, feats, is_ref, out);
    (void)in_sizes; (void)n_in; (void)out_size; (void)ws_size;
}